// Round 4
// baseline (327.533 us; speedup 1.0000x reference)
//
#include <hip/hip_runtime.h>

#define BB 4
#define LL 2048
#define EE 1024
#define HH 8
#define DD 128
#define OO 1024
#define MM (BB*LL)   // 8192

typedef __bf16 bf16;
typedef unsigned short u16;
typedef __bf16 bf16x8 __attribute__((ext_vector_type(8)));
typedef __bf16 bf16x4 __attribute__((ext_vector_type(4)));
typedef float  f32x4  __attribute__((ext_vector_type(4)));

__device__ __forceinline__ float rowmax16(float v) {
    v = fmaxf(v, __shfl_xor(v, 1));
    v = fmaxf(v, __shfl_xor(v, 2));
    v = fmaxf(v, __shfl_xor(v, 4));
    v = fmaxf(v, __shfl_xor(v, 8));
    return v;
}
__device__ __forceinline__ float rowsum16(float v) {
    v += __shfl_xor(v, 1);
    v += __shfl_xor(v, 2);
    v += __shfl_xor(v, 4);
    v += __shfl_xor(v, 8);
    return v;
}

// ---------------------------------------------------------------------------
// dtype detector: bf16 N(0,1) data -> nearly all u16 have exponent field in
// [117,132]; f32 data -> only the high halves (~256/512) do. mode=1 => bf16.
// ---------------------------------------------------------------------------
__global__ void detect_kernel(const u16* __restrict__ data, int* __restrict__ mode) {
    if (threadIdx.x == 0 && blockIdx.x == 0) {
        int cnt = 0;
        for (int i = 0; i < 512; i++) {
            int e = (data[i] >> 7) & 0xFF;
            if (e >= 117 && e <= 132) cnt++;
        }
        *mode = (cnt > 400) ? 1 : 0;
    }
}

__global__ __launch_bounds__(256) void fill_kernel(float* __restrict__ out, float v, int n) {
    int i = blockIdx.x * 256 + threadIdx.x;
    if (i < n) out[i] = v;
}

// ---------------------------------------------------------------------------
// w [H, E, D] (f32 or bf16)  ->  wT [H, D, E] bf16
// ---------------------------------------------------------------------------
__global__ __launch_bounds__(256) void wtrans_kernel(const void* __restrict__ in,
                                                     bf16* __restrict__ outT,
                                                     const int* __restrict__ mode) {
    int idx = blockIdx.x * 256 + threadIdx.x;   // over H*E*D/4
    int i4 = idx * 4;
    int h = i4 >> 17;            // E*D = 131072
    int rem = i4 & 131071;
    int e = rem >> 7;            // D = 128
    int d = rem & 127;
    size_t ob = ((size_t)h * DD + d) * EE + e;
    if (*mode) {
        bf16x4 v = *(const bf16x4*)((const bf16*)in + i4);
        outT[ob]          = v[0];
        outT[ob + EE]     = v[1];
        outT[ob + 2 * EE] = v[2];
        outT[ob + 3 * EE] = v[3];
    } else {
        float4 v = *(const float4*)((const float*)in + i4);
        outT[ob]          = (bf16)v.x;
        outT[ob + EE]     = (bf16)v.y;
        outT[ob + 2 * EE] = (bf16)v.z;
        outT[ob + 3 * EE] = (bf16)v.w;
    }
}

// ---------------------------------------------------------------------------
// X [M, E] (f32 or bf16), WT [H, D, E] bf16 -> outX = sigmoid(X @ W_h) bf16
// [H, M, D]; optionally also outXT [H, B, D, L] (for attention V tr-loads)
// ---------------------------------------------------------------------------
__global__ __launch_bounds__(256) void proj_gemm_kernel(const void* __restrict__ X,
                                                        const bf16* __restrict__ WT,
                                                        bf16* __restrict__ outX,
                                                        bf16* __restrict__ outXT,
                                                        const int* __restrict__ mode) {
    __shared__ __align__(16) bf16 As[64 * 32];
    __shared__ __align__(16) bf16 Bs[128 * 32];
    const int md = *mode;
    const int t = threadIdx.x;
    const int w = t >> 6, l = t & 63;
    const int lr = l & 15, lg = l >> 4;
    const int h = blockIdx.y;
    const int m0 = blockIdx.x * 64;
    const bf16* WTh = WT + (size_t)h * DD * EE;

    f32x4 acc[8];
    const f32x4 zero = {0.f, 0.f, 0.f, 0.f};
#pragma unroll
    for (int n = 0; n < 8; n++) acc[n] = zero;

    for (int kt = 0; kt < EE / 32; ++kt) {
        const int k0 = kt * 32;
        __syncthreads();
        {   // stage A: 64 rows x 4 chunks of 8 elems; one chunk per thread
            int row = t >> 2, cc = t & 3;
            bf16x8 v;
            if (md) {
                v = *(const bf16x8*)((const bf16*)X + (size_t)(m0 + row) * EE + k0 + cc * 8);
            } else {
                const float* src = (const float*)X + (size_t)(m0 + row) * EE + k0 + cc * 8;
                float4 f0 = *(const float4*)(src);
                float4 f1 = *(const float4*)(src + 4);
                v[0] = (bf16)f0.x; v[1] = (bf16)f0.y; v[2] = (bf16)f0.z; v[3] = (bf16)f0.w;
                v[4] = (bf16)f1.x; v[5] = (bf16)f1.y; v[6] = (bf16)f1.z; v[7] = (bf16)f1.w;
            }
            *(bf16x8*)(As + row * 32 + (((cc ^ (row & 3))) << 3)) = v;
        }
#pragma unroll
        for (int p = 0; p < 2; p++) {   // stage B: 128 rows x 4 chunks
            int id = p * 256 + t;
            int row = id >> 2, cc = id & 3;
            bf16x8 v = *(const bf16x8*)(WTh + (size_t)row * EE + k0 + cc * 8);
            *(bf16x8*)(Bs + row * 32 + (((cc ^ (row & 3))) << 3)) = v;
        }
        __syncthreads();
        const int arow = w * 16 + lr;
        bf16x8 a = *(const bf16x8*)(As + arow * 32 + (((lg ^ (arow & 3))) << 3));
#pragma unroll
        for (int n = 0; n < 8; n++) {
            int brow = n * 16 + lr;
            bf16x8 b = *(const bf16x8*)(Bs + brow * 32 + (((lg ^ (brow & 3))) << 3));
            acc[n] = __builtin_amdgcn_mfma_f32_16x16x32_bf16(a, b, acc[n], 0, 0, 0);
        }
    }
    // epilogue: sigmoid + stores
    const int b_idx = m0 / LL;
    const int l0 = m0 - b_idx * LL;
#pragma unroll
    for (int n = 0; n < 8; n++) {
        const int col = n * 16 + lr;
        float s[4];
#pragma unroll
        for (int j = 0; j < 4; j++) {
            s[j] = 1.0f / (1.0f + __expf(-acc[n][j]));
            int mrow = m0 + w * 16 + lg * 4 + j;
            outX[((size_t)h * MM + mrow) * DD + col] = (bf16)s[j];
        }
        if (outXT) {
            bf16x4 pk;
            pk[0] = (bf16)s[0]; pk[1] = (bf16)s[1]; pk[2] = (bf16)s[2]; pk[3] = (bf16)s[3];
            int lrow = l0 + w * 16 + lg * 4;
            *(bf16x4*)(outXT + (((size_t)h * BB + b_idx) * DD + col) * LL + lrow) = pk;
        }
    }
}

// ---------------------------------------------------------------------------
// attention: QX,KX [H, M, D] bf16; KXT [H, B, D, L] bf16 -> AO [M, H*D] bf16
// ---------------------------------------------------------------------------
__global__ __launch_bounds__(256) void attn_kernel(const bf16* __restrict__ QX,
                                                   const bf16* __restrict__ KX,
                                                   const bf16* __restrict__ KXT,
                                                   bf16* __restrict__ AO) {
    __shared__ __align__(16) bf16 Kl[64 * 128];
    __shared__ __align__(16) bf16 Vt[128 * 64];
    __shared__ __align__(16) bf16 Pl[4][16 * 64];
    const int t = threadIdx.x;
    const int w = t >> 6, l = t & 63;
    const int lr = l & 15, lg = l >> 4;
    const int bh = blockIdx.y;
    const int h = bh & 7, b = bh >> 3;
    const int q0 = blockIdx.x * 64;
    const bf16* qxh = QX + ((size_t)h * MM + b * LL) * DD;
    const bf16* kxh = KX + ((size_t)h * MM + b * LL) * DD;
    const bf16* kxt = KXT + ((size_t)(h * BB + b)) * DD * LL;

    bf16x8 qf[4];
    const int qrow = q0 + w * 16 + lr;
#pragma unroll
    for (int s = 0; s < 4; s++)
        qf[s] = *(const bf16x8*)(qxh + (size_t)qrow * DD + s * 32 + lg * 8);

    f32x4 oacc[8];
    const f32x4 zero = {0.f, 0.f, 0.f, 0.f};
#pragma unroll
    for (int n = 0; n < 8; n++) oacc[n] = zero;
    float mrun[4], lrun[4];
#pragma unroll
    for (int j = 0; j < 4; j++) { mrun[j] = -1e30f; lrun[j] = 0.0f; }

    for (int kt = 0; kt < LL / 64; ++kt) {
        const int kv0 = kt * 64;
        __syncthreads();
#pragma unroll
        for (int p = 0; p < 4; p++) {   // stage K [64][128]
            int id = p * 256 + t;
            int row = id >> 4, cc = id & 15;
            bf16x8 v = *(const bf16x8*)(kxh + (size_t)(kv0 + row) * DD + cc * 8);
            *(bf16x8*)(Kl + row * 128 + (((cc ^ (row & 15))) << 3)) = v;
        }
#pragma unroll
        for (int p = 0; p < 4; p++) {   // stage V^T [128][64]
            int id = p * 256 + t;
            int row = id >> 3, cc = id & 7;
            bf16x8 v = *(const bf16x8*)(kxt + (size_t)row * LL + kv0 + cc * 8);
            *(bf16x8*)(Vt + row * 64 + (((cc ^ (row & 7))) << 3)) = v;
        }
        __syncthreads();

        f32x4 sa[4];
#pragma unroll
        for (int n = 0; n < 4; n++) {
            sa[n] = zero;
#pragma unroll
            for (int ks = 0; ks < 4; ks++) {
                int brow = n * 16 + lr;
                bf16x8 kb = *(const bf16x8*)(Kl + brow * 128 + ((((ks * 4 + lg) ^ (brow & 15))) << 3));
                sa[n] = __builtin_amdgcn_mfma_f32_16x16x32_bf16(qf[ks], kb, sa[n], 0, 0, 0);
            }
            sa[n] *= 0.08838834764831845f;   // 1/sqrt(128)
        }
        float mnew[4], fac[4];
#pragma unroll
        for (int j = 0; j < 4; j++) {
            float v = fmaxf(fmaxf(sa[0][j], sa[1][j]), fmaxf(sa[2][j], sa[3][j]));
            v = rowmax16(v);
            mnew[j] = fmaxf(mrun[j], v);
            fac[j] = __expf(mrun[j] - mnew[j]);
            mrun[j] = mnew[j];
        }
        float psum[4] = {0.f, 0.f, 0.f, 0.f};
#pragma unroll
        for (int n = 0; n < 4; n++) {
#pragma unroll
            for (int j = 0; j < 4; j++) {
                float p = __expf(sa[n][j] - mnew[j]);
                psum[j] += p;
                int prow = lg * 4 + j, pcol = n * 16 + lr;
                Pl[w][prow * 64 + ((((pcol >> 3) ^ (prow & 7))) << 3) + (pcol & 7)] = (bf16)p;
            }
        }
        __syncthreads();   // order P scalar-stores vs vector-loads
#pragma unroll
        for (int j = 0; j < 4; j++) {
            float s = rowsum16(psum[j]);
            lrun[j] = lrun[j] * fac[j] + s;
        }
#pragma unroll
        for (int n = 0; n < 8; n++) {
#pragma unroll
            for (int j = 0; j < 4; j++) oacc[n][j] *= fac[j];
        }
#pragma unroll
        for (int n = 0; n < 8; n++) {
#pragma unroll
            for (int ks = 0; ks < 2; ks++) {
                bf16x8 pa = *(const bf16x8*)(&Pl[w][lr * 64 + ((((ks * 4 + lg) ^ (lr & 7))) << 3)]);
                int vrow = n * 16 + lr;
                bf16x8 vb = *(const bf16x8*)(Vt + vrow * 64 + ((((ks * 4 + lg) ^ (vrow & 7))) << 3));
                oacc[n] = __builtin_amdgcn_mfma_f32_16x16x32_bf16(pa, vb, oacc[n], 0, 0, 0);
            }
        }
    }
    const int arow = b * LL + q0 + w * 16;
#pragma unroll
    for (int n = 0; n < 8; n++) {
        const int col = h * DD + n * 16 + lr;
#pragma unroll
        for (int j = 0; j < 4; j++) {
            float o = oacc[n][j] / lrun[j];
            AO[(size_t)(arow + lg * 4 + j) * (HH * DD) + col] = (bf16)o;
        }
    }
}

// ---------------------------------------------------------------------------
// final projection: AO [M,1024] bf16 @ proj_w^T + bias -> d_out FLOAT [M,1024]
// proj_w [OUT, H*D] (f32 or bf16), proj_b [OUT] (f32 or bf16)
// ---------------------------------------------------------------------------
__global__ __launch_bounds__(256) void out_gemm_kernel(const bf16* __restrict__ A,
                                                       const void* __restrict__ PW,
                                                       const void* __restrict__ PB,
                                                       float* __restrict__ Cout,
                                                       const int* __restrict__ mode) {
    __shared__ __align__(16) bf16 As[64 * 32];
    __shared__ __align__(16) bf16 Bs[128 * 32];
    const int md = *mode;
    const int t = threadIdx.x;
    const int w = t >> 6, l = t & 63;
    const int lr = l & 15, lg = l >> 4;
    const int m0 = blockIdx.x * 64;
    const int n0 = blockIdx.y * 128;

    f32x4 acc[8];
    const f32x4 zero = {0.f, 0.f, 0.f, 0.f};
#pragma unroll
    for (int n = 0; n < 8; n++) acc[n] = zero;

    for (int kt = 0; kt < (HH * DD) / 32; ++kt) {
        const int k0 = kt * 32;
        __syncthreads();
        {   // stage A (bf16 source)
            int row = t >> 2, cc = t & 3;
            bf16x8 v = *(const bf16x8*)(A + (size_t)(m0 + row) * (HH * DD) + k0 + cc * 8);
            *(bf16x8*)(As + row * 32 + (((cc ^ (row & 3))) << 3)) = v;
        }
#pragma unroll
        for (int p = 0; p < 2; p++) {   // stage B from proj_w
            int id = p * 256 + t;
            int row = id >> 2, cc = id & 3;
            bf16x8 v;
            if (md) {
                v = *(const bf16x8*)((const bf16*)PW + (size_t)(n0 + row) * (HH * DD) + k0 + cc * 8);
            } else {
                const float* src = (const float*)PW + (size_t)(n0 + row) * (HH * DD) + k0 + cc * 8;
                float4 f0 = *(const float4*)(src);
                float4 f1 = *(const float4*)(src + 4);
                v[0] = (bf16)f0.x; v[1] = (bf16)f0.y; v[2] = (bf16)f0.z; v[3] = (bf16)f0.w;
                v[4] = (bf16)f1.x; v[5] = (bf16)f1.y; v[6] = (bf16)f1.z; v[7] = (bf16)f1.w;
            }
            *(bf16x8*)(Bs + row * 32 + (((cc ^ (row & 3))) << 3)) = v;
        }
        __syncthreads();
        const int arow = w * 16 + lr;
        bf16x8 a = *(const bf16x8*)(As + arow * 32 + (((lg ^ (arow & 3))) << 3));
#pragma unroll
        for (int n = 0; n < 8; n++) {
            int brow = n * 16 + lr;
            bf16x8 b = *(const bf16x8*)(Bs + brow * 32 + (((lg ^ (brow & 3))) << 3));
            acc[n] = __builtin_amdgcn_mfma_f32_16x16x32_bf16(a, b, acc[n], 0, 0, 0);
        }
    }
#pragma unroll
    for (int n = 0; n < 8; n++) {
        const int gcol = n0 + n * 16 + lr;
        const float bias = md ? (float)((const bf16*)PB)[gcol] : ((const float*)PB)[gcol];
#pragma unroll
        for (int j = 0; j < 4; j++) {
            int grow = m0 + w * 16 + lg * 4 + j;
            Cout[(size_t)grow * OO + gcol] = acc[n][j] + bias;   // f32 out
        }
    }
}

extern "C" void kernel_launch(void* const* d_in, const int* in_sizes, int n_in,
                              void* d_out, int out_size, void* d_ws, size_t ws_size,
                              hipStream_t stream) {
    (void)in_sizes; (void)n_in;
    float* out = (float*)d_out;

    const size_t NEED = ((size_t)(2 + 2 + 16 + 16 + 16 + 16) << 20) + 256;
    if (ws_size < NEED) {
        // diagnostic: report ws_size (in MiB) through the output
        hipLaunchKernelGGL(fill_kernel, dim3((out_size + 255) / 256), dim3(256), 0, stream,
                           out, (float)(ws_size >> 20), out_size);
        return;
    }

    int* mode = (int*)d_ws;
    bf16* base = (bf16*)((char*)d_ws + 256);
    bf16* wkT = base;                              // [H, D, E]   2 MiB
    bf16* wqT = wkT + (size_t)HH * DD * EE;        // [H, D, E]   2 MiB
    bf16* kx  = wqT + (size_t)HH * DD * EE;        // [H, M, D]  16 MiB
    bf16* qx  = kx  + (size_t)HH * MM * DD;        // [H, M, D]  16 MiB
    bf16* kxT = qx  + (size_t)HH * MM * DD;        // [H, B, D, L] 16 MiB
    bf16* ao  = kxT + (size_t)HH * MM * DD;        // [M, H*D]   16 MiB

    hipLaunchKernelGGL(detect_kernel, dim3(1), dim3(64), 0, stream, (const u16*)d_in[0], mode);
    hipLaunchKernelGGL(wtrans_kernel, dim3(HH * EE * DD / 4 / 256), dim3(256), 0, stream, d_in[2], wkT, mode);
    hipLaunchKernelGGL(wtrans_kernel, dim3(HH * EE * DD / 4 / 256), dim3(256), 0, stream, d_in[3], wqT, mode);
    hipLaunchKernelGGL(proj_gemm_kernel, dim3(MM / 64, HH), dim3(256), 0, stream, d_in[0], wkT, kx, kxT, mode);
    hipLaunchKernelGGL(proj_gemm_kernel, dim3(MM / 64, HH), dim3(256), 0, stream, d_in[1], wqT, qx, (bf16*)nullptr, mode);
    hipLaunchKernelGGL(attn_kernel, dim3(LL / 64, BB * HH), dim3(256), 0, stream, qx, kx, kxT, ao);
    hipLaunchKernelGGL(out_gemm_kernel, dim3(MM / 64, OO / 128), dim3(256), 0, stream, ao, d_in[4], d_in[5], out, mode);
}

// Round 5
// 300.157 us; speedup vs baseline: 1.0912x; 1.0912x over previous
//
#include <hip/hip_runtime.h>

#define BB 4
#define LL 2048
#define EE 1024
#define HH 8
#define DD 128
#define OO 1024
#define MM (BB*LL)   // 8192

#define QBLK 128
#define KVBLK 64
#define NT (LL / KVBLK)

typedef __bf16 bf16;
typedef unsigned short u16;
typedef __bf16 bf16x8 __attribute__((ext_vector_type(8)));
typedef __bf16 bf16x4 __attribute__((ext_vector_type(4)));
typedef float  f32x4  __attribute__((ext_vector_type(4)));

__device__ __forceinline__ float rowmax16(float v) {
    v = fmaxf(v, __shfl_xor(v, 1));
    v = fmaxf(v, __shfl_xor(v, 2));
    v = fmaxf(v, __shfl_xor(v, 4));
    v = fmaxf(v, __shfl_xor(v, 8));
    return v;
}
__device__ __forceinline__ float rowsum16(float v) {
    v += __shfl_xor(v, 1);
    v += __shfl_xor(v, 2);
    v += __shfl_xor(v, 4);
    v += __shfl_xor(v, 8);
    return v;
}

// ---------------------------------------------------------------------------
// dtype detector: bf16 N(0,1) data -> nearly all u16 exponent fields in
// [117,132]; f32 data -> only ~half. mode=1 => bf16 inputs.
// ---------------------------------------------------------------------------
__global__ void detect_kernel(const u16* __restrict__ data, int* __restrict__ mode) {
    if (threadIdx.x == 0 && blockIdx.x == 0) {
        int cnt = 0;
        for (int i = 0; i < 512; i++) {
            int e = (data[i] >> 7) & 0xFF;
            if (e >= 117 && e <= 132) cnt++;
        }
        *mode = (cnt > 400) ? 1 : 0;
    }
}

__global__ __launch_bounds__(256) void fill_kernel(float* __restrict__ out, float v, int n) {
    int i = blockIdx.x * 256 + threadIdx.x;
    if (i < n) out[i] = v;
}

// ---------------------------------------------------------------------------
// w [H, E, D] (f32 or bf16)  ->  wT [H, D, E] bf16
// ---------------------------------------------------------------------------
__global__ __launch_bounds__(256) void wtrans_kernel(const void* __restrict__ in,
                                                     bf16* __restrict__ outT,
                                                     const int* __restrict__ mode) {
    int idx = blockIdx.x * 256 + threadIdx.x;   // over H*E*D/4
    int i4 = idx * 4;
    int h = i4 >> 17;            // E*D = 131072
    int rem = i4 & 131071;
    int e = rem >> 7;            // D = 128
    int d = rem & 127;
    size_t ob = ((size_t)h * DD + d) * EE + e;
    if (*mode) {
        bf16x4 v = *(const bf16x4*)((const bf16*)in + i4);
        outT[ob]          = v[0];
        outT[ob + EE]     = v[1];
        outT[ob + 2 * EE] = v[2];
        outT[ob + 3 * EE] = v[3];
    } else {
        float4 v = *(const float4*)((const float*)in + i4);
        outT[ob]          = (bf16)v.x;
        outT[ob + EE]     = (bf16)v.y;
        outT[ob + 2 * EE] = (bf16)v.z;
        outT[ob + 3 * EE] = (bf16)v.w;
    }
}

// ---------------------------------------------------------------------------
// X [M, E] (f32 or bf16), WT [H, D, E] bf16 -> outX = sigmoid(X @ W_h) bf16
// [H, M, D]; optionally also outXT [H, B, D, L] (for attention V tr-loads)
// ---------------------------------------------------------------------------
__global__ __launch_bounds__(256) void proj_gemm_kernel(const void* __restrict__ X,
                                                        const bf16* __restrict__ WT,
                                                        bf16* __restrict__ outX,
                                                        bf16* __restrict__ outXT,
                                                        const int* __restrict__ mode) {
    __shared__ __align__(16) bf16 As[64 * 32];
    __shared__ __align__(16) bf16 Bs[128 * 32];
    const int md = *mode;
    const int t = threadIdx.x;
    const int w = t >> 6, l = t & 63;
    const int lr = l & 15, lg = l >> 4;
    const int h = blockIdx.y;
    const int m0 = blockIdx.x * 64;
    const bf16* WTh = WT + (size_t)h * DD * EE;

    f32x4 acc[8];
    const f32x4 zero = {0.f, 0.f, 0.f, 0.f};
#pragma unroll
    for (int n = 0; n < 8; n++) acc[n] = zero;

    for (int kt = 0; kt < EE / 32; ++kt) {
        const int k0 = kt * 32;
        __syncthreads();
        {   // stage A: 64 rows x 4 chunks of 8 elems; one chunk per thread
            int row = t >> 2, cc = t & 3;
            bf16x8 v;
            if (md) {
                v = *(const bf16x8*)((const bf16*)X + (size_t)(m0 + row) * EE + k0 + cc * 8);
            } else {
                const float* src = (const float*)X + (size_t)(m0 + row) * EE + k0 + cc * 8;
                float4 f0 = *(const float4*)(src);
                float4 f1 = *(const float4*)(src + 4);
                v[0] = (bf16)f0.x; v[1] = (bf16)f0.y; v[2] = (bf16)f0.z; v[3] = (bf16)f0.w;
                v[4] = (bf16)f1.x; v[5] = (bf16)f1.y; v[6] = (bf16)f1.z; v[7] = (bf16)f1.w;
            }
            *(bf16x8*)(As + row * 32 + (((cc ^ (row & 3))) << 3)) = v;
        }
#pragma unroll
        for (int p = 0; p < 2; p++) {   // stage B: 128 rows x 4 chunks
            int id = p * 256 + t;
            int row = id >> 2, cc = id & 3;
            bf16x8 v = *(const bf16x8*)(WTh + (size_t)row * EE + k0 + cc * 8);
            *(bf16x8*)(Bs + row * 32 + (((cc ^ (row & 3))) << 3)) = v;
        }
        __syncthreads();
        const int arow = w * 16 + lr;
        bf16x8 a = *(const bf16x8*)(As + arow * 32 + (((lg ^ (arow & 3))) << 3));
#pragma unroll
        for (int n = 0; n < 8; n++) {
            int brow = n * 16 + lr;
            bf16x8 b = *(const bf16x8*)(Bs + brow * 32 + (((lg ^ (brow & 3))) << 3));
            acc[n] = __builtin_amdgcn_mfma_f32_16x16x32_bf16(a, b, acc[n], 0, 0, 0);
        }
    }
    // epilogue: sigmoid + stores
    const int b_idx = m0 / LL;
    const int l0 = m0 - b_idx * LL;
#pragma unroll
    for (int n = 0; n < 8; n++) {
        const int col = n * 16 + lr;
        float s[4];
#pragma unroll
        for (int j = 0; j < 4; j++) {
            s[j] = 1.0f / (1.0f + __expf(-acc[n][j]));
            int mrow = m0 + w * 16 + lg * 4 + j;
            outX[((size_t)h * MM + mrow) * DD + col] = (bf16)s[j];
        }
        if (outXT) {
            bf16x4 pk;
            pk[0] = (bf16)s[0]; pk[1] = (bf16)s[1]; pk[2] = (bf16)s[2]; pk[3] = (bf16)s[3];
            int lrow = l0 + w * 16 + lg * 4;
            *(bf16x4*)(outXT + (((size_t)h * BB + b_idx) * DD + col) * LL + lrow) = pk;
        }
    }
}

// ---------------------------------------------------------------------------
// attention: QX,KX [H, M, D] bf16; KXT [H, B, D, L] bf16 -> AO [M, H*D] bf16
// grid (L/QBLK, B*H); 512 threads = 8 waves, wave w owns q-rows q0+w*16..+15.
// LDS double-buffered K/V tiles + register prefetch; 1 barrier per KV tile.
// Online softmax with defer-max (THR=8).
// ---------------------------------------------------------------------------
__global__ __launch_bounds__(512, 4) void attn_kernel(const bf16* __restrict__ QX,
                                                      const bf16* __restrict__ KX,
                                                      const bf16* __restrict__ KXT,
                                                      bf16* __restrict__ AO) {
    __shared__ __align__(16) bf16 Kl[2][KVBLK * 128];   // 32 KiB
    __shared__ __align__(16) bf16 Vt[2][128 * KVBLK];   // 32 KiB
    __shared__ __align__(16) bf16 Pl[8][16 * 64];       // 16 KiB
    const int t = threadIdx.x;
    const int w = t >> 6, l = t & 63;
    const int lr = l & 15, lg = l >> 4;
    const int bh = blockIdx.y;
    const int h = bh & 7, b = bh >> 3;
    const int q0 = blockIdx.x * QBLK;
    const float c = 0.08838834764831845f;   // 1/sqrt(128)
    const bf16* qxh = QX + ((size_t)h * MM + b * LL) * DD;
    const bf16* kxh = KX + ((size_t)h * MM + b * LL) * DD;
    const bf16* kxt = KXT + ((size_t)(h * BB + b)) * DD * LL;

    // hoisted staging geometry (2 chunks each for K and V per thread)
    const int kid1 = 512 + t;
    const int krow0 = t >> 4,    kcc0 = t & 15;
    const int krow1 = kid1 >> 4, kcc1 = kid1 & 15;
    const int vrow0 = t >> 3,    vcc0 = t & 7;
    const int vrow1 = kid1 >> 3, vcc1 = kid1 & 7;
    const bf16* kp0 = kxh + (size_t)krow0 * DD + kcc0 * 8;
    const bf16* kp1 = kxh + (size_t)krow1 * DD + kcc1 * 8;
    const bf16* vp0 = kxt + (size_t)vrow0 * LL + vcc0 * 8;
    const bf16* vp1 = kxt + (size_t)vrow1 * LL + vcc1 * 8;
    const int kw0 = krow0 * 128 + ((kcc0 ^ (krow0 & 15)) << 3);
    const int kw1 = krow1 * 128 + ((kcc1 ^ (krow1 & 15)) << 3);
    const int vw0 = vrow0 * 64 + ((vcc0 ^ (vrow0 & 7)) << 3);
    const int vw1 = vrow1 * 64 + ((vcc1 ^ (vrow1 & 7)) << 3);

    // Q fragments, register resident
    bf16x8 qf[4];
    const int qrow = q0 + w * 16 + lr;
#pragma unroll
    for (int s = 0; s < 4; s++)
        qf[s] = *(const bf16x8*)(qxh + (size_t)qrow * DD + s * 32 + lg * 8);

    // prologue: tile 0 -> regs -> buf0; issue tile-1 loads
    bf16x8 rk0 = *(const bf16x8*)(kp0);
    bf16x8 rk1 = *(const bf16x8*)(kp1);
    bf16x8 rv0 = *(const bf16x8*)(vp0);
    bf16x8 rv1 = *(const bf16x8*)(vp1);
    *(bf16x8*)(Kl[0] + kw0) = rk0;
    *(bf16x8*)(Kl[0] + kw1) = rk1;
    *(bf16x8*)(Vt[0] + vw0) = rv0;
    *(bf16x8*)(Vt[0] + vw1) = rv1;
    rk0 = *(const bf16x8*)(kp0 + (size_t)KVBLK * DD);
    rk1 = *(const bf16x8*)(kp1 + (size_t)KVBLK * DD);
    rv0 = *(const bf16x8*)(vp0 + KVBLK);
    rv1 = *(const bf16x8*)(vp1 + KVBLK);
    __syncthreads();

    f32x4 oacc[8];
    const f32x4 zero = {0.f, 0.f, 0.f, 0.f};
#pragma unroll
    for (int n = 0; n < 8; n++) oacc[n] = zero;
    float mrun[4], lrun[4];
#pragma unroll
    for (int j = 0; j < 4; j++) { mrun[j] = -1e30f; lrun[j] = 0.0f; }

    for (int kt = 0; kt < NT; ++kt) {
        const int cur = kt & 1;
        // stage tile kt+1 into alt buffer; issue loads for tile kt+2
        if (kt + 1 < NT) {
            *(bf16x8*)(Kl[cur ^ 1] + kw0) = rk0;
            *(bf16x8*)(Kl[cur ^ 1] + kw1) = rk1;
            *(bf16x8*)(Vt[cur ^ 1] + vw0) = rv0;
            *(bf16x8*)(Vt[cur ^ 1] + vw1) = rv1;
            if (kt + 2 < NT) {
                const size_t ko = (size_t)(kt + 2) * KVBLK * DD;
                const int vo = (kt + 2) * KVBLK;
                rk0 = *(const bf16x8*)(kp0 + ko);
                rk1 = *(const bf16x8*)(kp1 + ko);
                rv0 = *(const bf16x8*)(vp0 + vo);
                rv1 = *(const bf16x8*)(vp1 + vo);
            }
        }
        const bf16* KlC = Kl[cur];
        const bf16* VtC = Vt[cur];

        // scores: S[16 q x 64 kv] = Q K^T  (unscaled; scale folded into exp)
        f32x4 sa[4];
#pragma unroll
        for (int n = 0; n < 4; n++) {
            sa[n] = zero;
#pragma unroll
            for (int ks = 0; ks < 4; ks++) {
                int brow = n * 16 + lr;
                bf16x8 kb = *(const bf16x8*)(KlC + brow * 128 + ((((ks * 4 + lg) ^ (brow & 15))) << 3));
                sa[n] = __builtin_amdgcn_mfma_f32_16x16x32_bf16(qf[ks], kb, sa[n], 0, 0, 0);
            }
        }
        // online softmax with defer-max
        float pmax[4];
#pragma unroll
        for (int j = 0; j < 4; j++) {
            float v = fmaxf(fmaxf(sa[0][j], sa[1][j]), fmaxf(sa[2][j], sa[3][j]));
            pmax[j] = rowmax16(v) * c;
        }
        float grow = fmaxf(fmaxf(pmax[0] - mrun[0], pmax[1] - mrun[1]),
                           fmaxf(pmax[2] - mrun[2], pmax[3] - mrun[3]));
        if (!__all(grow <= 8.0f)) {
#pragma unroll
            for (int j = 0; j < 4; j++) {
                float mnew = fmaxf(mrun[j], pmax[j]);
                float fac = __expf(mrun[j] - mnew);
                lrun[j] *= fac;
                mrun[j] = mnew;
#pragma unroll
                for (int n = 0; n < 8; n++) oacc[n][j] *= fac;
            }
        }
        float psum[4] = {0.f, 0.f, 0.f, 0.f};
#pragma unroll
        for (int n = 0; n < 4; n++) {
#pragma unroll
            for (int j = 0; j < 4; j++) {
                float p = __expf(__fmaf_rn(sa[n][j], c, -mrun[j]));
                psum[j] += p;
                int prow = lg * 4 + j, pcol = n * 16 + lr;
                Pl[w][prow * 64 + ((((pcol >> 3) ^ (prow & 7))) << 3) + (pcol & 7)] = (bf16)p;
            }
        }
#pragma unroll
        for (int j = 0; j < 4; j++) lrun[j] += rowsum16(psum[j]);
        // wave-local ordering: P scalar-stores above vs vector-loads below
        asm volatile("s_waitcnt lgkmcnt(0)" ::: "memory");
        __builtin_amdgcn_sched_barrier(0);
        // PV: O += P V
        bf16x8 pa0 = *(const bf16x8*)(&Pl[w][lr * 64 + (((lg ^ (lr & 7))) << 3)]);
        bf16x8 pa1 = *(const bf16x8*)(&Pl[w][lr * 64 + ((((4 + lg) ^ (lr & 7))) << 3)]);
#pragma unroll
        for (int n = 0; n < 8; n++) {
            int vrow = n * 16 + lr;
            bf16x8 vb0 = *(const bf16x8*)(VtC + vrow * 64 + (((lg ^ (vrow & 7))) << 3));
            oacc[n] = __builtin_amdgcn_mfma_f32_16x16x32_bf16(pa0, vb0, oacc[n], 0, 0, 0);
            bf16x8 vb1 = *(const bf16x8*)(VtC + vrow * 64 + ((((4 + lg) ^ (vrow & 7))) << 3));
            oacc[n] = __builtin_amdgcn_mfma_f32_16x16x32_bf16(pa1, vb1, oacc[n], 0, 0, 0);
        }
        __syncthreads();
    }
    // epilogue
    const int arow = b * LL + q0 + w * 16;
#pragma unroll
    for (int n = 0; n < 8; n++) {
        const int col = h * DD + n * 16 + lr;
#pragma unroll
        for (int j = 0; j < 4; j++) {
            float o = oacc[n][j] / lrun[j];
            AO[(size_t)(arow + lg * 4 + j) * (HH * DD) + col] = (bf16)o;
        }
    }
}

// ---------------------------------------------------------------------------
// final projection: AO [M,1024] bf16 @ proj_w^T + bias -> d_out FLOAT [M,1024]
// ---------------------------------------------------------------------------
__global__ __launch_bounds__(256) void out_gemm_kernel(const bf16* __restrict__ A,
                                                       const void* __restrict__ PW,
                                                       const void* __restrict__ PB,
                                                       float* __restrict__ Cout,
                                                       const int* __restrict__ mode) {
    __shared__ __align__(16) bf16 As[64 * 32];
    __shared__ __align__(16) bf16 Bs[128 * 32];
    const int md = *mode;
    const int t = threadIdx.x;
    const int w = t >> 6, l = t & 63;
    const int lr = l & 15, lg = l >> 4;
    const int m0 = blockIdx.x * 64;
    const int n0 = blockIdx.y * 128;

    f32x4 acc[8];
    const f32x4 zero = {0.f, 0.f, 0.f, 0.f};
#pragma unroll
    for (int n = 0; n < 8; n++) acc[n] = zero;

    for (int kt = 0; kt < (HH * DD) / 32; ++kt) {
        const int k0 = kt * 32;
        __syncthreads();
        {   // stage A (bf16 source)
            int row = t >> 2, cc = t & 3;
            bf16x8 v = *(const bf16x8*)(A + (size_t)(m0 + row) * (HH * DD) + k0 + cc * 8);
            *(bf16x8*)(As + row * 32 + (((cc ^ (row & 3))) << 3)) = v;
        }
#pragma unroll
        for (int p = 0; p < 2; p++) {   // stage B from proj_w
            int id = p * 256 + t;
            int row = id >> 2, cc = id & 3;
            bf16x8 v;
            if (md) {
                v = *(const bf16x8*)((const bf16*)PW + (size_t)(n0 + row) * (HH * DD) + k0 + cc * 8);
            } else {
                const float* src = (const float*)PW + (size_t)(n0 + row) * (HH * DD) + k0 + cc * 8;
                float4 f0 = *(const float4*)(src);
                float4 f1 = *(const float4*)(src + 4);
                v[0] = (bf16)f0.x; v[1] = (bf16)f0.y; v[2] = (bf16)f0.z; v[3] = (bf16)f0.w;
                v[4] = (bf16)f1.x; v[5] = (bf16)f1.y; v[6] = (bf16)f1.z; v[7] = (bf16)f1.w;
            }
            *(bf16x8*)(Bs + row * 32 + (((cc ^ (row & 3))) << 3)) = v;
        }
        __syncthreads();
        const int arow = w * 16 + lr;
        bf16x8 a = *(const bf16x8*)(As + arow * 32 + (((lg ^ (arow & 3))) << 3));
#pragma unroll
        for (int n = 0; n < 8; n++) {
            int brow = n * 16 + lr;
            bf16x8 b = *(const bf16x8*)(Bs + brow * 32 + (((lg ^ (brow & 3))) << 3));
            acc[n] = __builtin_amdgcn_mfma_f32_16x16x32_bf16(a, b, acc[n], 0, 0, 0);
        }
    }
#pragma unroll
    for (int n = 0; n < 8; n++) {
        const int gcol = n0 + n * 16 + lr;
        const float bias = md ? (float)((const bf16*)PB)[gcol] : ((const float*)PB)[gcol];
#pragma unroll
        for (int j = 0; j < 4; j++) {
            int grow = m0 + w * 16 + lg * 4 + j;
            Cout[(size_t)grow * OO + gcol] = acc[n][j] + bias;   // f32 out
        }
    }
}

extern "C" void kernel_launch(void* const* d_in, const int* in_sizes, int n_in,
                              void* d_out, int out_size, void* d_ws, size_t ws_size,
                              hipStream_t stream) {
    (void)in_sizes; (void)n_in;
    float* out = (float*)d_out;

    const size_t NEED = ((size_t)(2 + 2 + 16 + 16 + 16 + 16) << 20) + 256;
    if (ws_size < NEED) {
        hipLaunchKernelGGL(fill_kernel, dim3((out_size + 255) / 256), dim3(256), 0, stream,
                           out, (float)(ws_size >> 20), out_size);
        return;
    }

    int* mode = (int*)d_ws;
    bf16* base = (bf16*)((char*)d_ws + 256);
    bf16* wkT = base;                              // [H, D, E]   2 MiB
    bf16* wqT = wkT + (size_t)HH * DD * EE;        // [H, D, E]   2 MiB
    bf16* kx  = wqT + (size_t)HH * DD * EE;        // [H, M, D]  16 MiB
    bf16* qx  = kx  + (size_t)HH * MM * DD;        // [H, M, D]  16 MiB
    bf16* kxT = qx  + (size_t)HH * MM * DD;        // [H, B, D, L] 16 MiB
    bf16* ao  = kxT + (size_t)HH * MM * DD;        // [M, H*D]   16 MiB

    hipLaunchKernelGGL(detect_kernel, dim3(1), dim3(64), 0, stream, (const u16*)d_in[0], mode);
    hipLaunchKernelGGL(wtrans_kernel, dim3(HH * EE * DD / 4 / 256), dim3(256), 0, stream, d_in[2], wkT, mode);
    hipLaunchKernelGGL(wtrans_kernel, dim3(HH * EE * DD / 4 / 256), dim3(256), 0, stream, d_in[3], wqT, mode);
    hipLaunchKernelGGL(proj_gemm_kernel, dim3(MM / 64, HH), dim3(256), 0, stream, d_in[0], wkT, kx, kxT, mode);
    hipLaunchKernelGGL(proj_gemm_kernel, dim3(MM / 64, HH), dim3(256), 0, stream, d_in[1], wqT, qx, (bf16*)nullptr, mode);
    hipLaunchKernelGGL(attn_kernel, dim3(LL / QBLK, BB * HH), dim3(512), 0, stream, qx, kx, kxT, ao);
    hipLaunchKernelGGL(out_gemm_kernel, dim3(MM / 64, OO / 128), dim3(256), 0, stream, ao, d_in[4], d_in[5], out, mode);
}

// Round 6
// 248.987 us; speedup vs baseline: 1.3155x; 1.2055x over previous
//
#include <hip/hip_runtime.h>

#define BB 4
#define LL 2048
#define EE 1024
#define HH 8
#define DD 128
#define OO 1024
#define MM (BB*LL)   // 8192

#define QBLK 128
#define KVBLK 64
#define NT (LL / KVBLK)

typedef __bf16 bf16;
typedef unsigned short u16;
typedef __bf16 bf16x8 __attribute__((ext_vector_type(8)));
typedef __bf16 bf16x4 __attribute__((ext_vector_type(4)));
typedef float  f32x4  __attribute__((ext_vector_type(4)));

__device__ __forceinline__ float rowsum16(float v) {
    v += __shfl_xor(v, 1);
    v += __shfl_xor(v, 2);
    v += __shfl_xor(v, 4);
    v += __shfl_xor(v, 8);
    return v;
}

// ---------------------------------------------------------------------------
// dtype detector: bf16 N(0,1) data -> nearly all u16 exponent fields in
// [117,132]; f32 data -> only ~half. mode=1 => bf16 inputs.
// ---------------------------------------------------------------------------
__global__ void detect_kernel(const u16* __restrict__ data, int* __restrict__ mode) {
    if (threadIdx.x == 0 && blockIdx.x == 0) {
        int cnt = 0;
        for (int i = 0; i < 512; i++) {
            int e = (data[i] >> 7) & 0xFF;
            if (e >= 117 && e <= 132) cnt++;
        }
        *mode = (cnt > 400) ? 1 : 0;
    }
}

__global__ __launch_bounds__(256) void fill_kernel(float* __restrict__ out, float v, int n) {
    int i = blockIdx.x * 256 + threadIdx.x;
    if (i < n) out[i] = v;
}

// ---------------------------------------------------------------------------
// w [H, E, D] (f32 or bf16)  ->  wT [H, D, E] bf16   (both weights, y=which)
// ---------------------------------------------------------------------------
__global__ __launch_bounds__(256) void wtrans_kernel(const void* __restrict__ in0,
                                                     const void* __restrict__ in1,
                                                     bf16* __restrict__ outT0,
                                                     bf16* __restrict__ outT1,
                                                     const int* __restrict__ mode) {
    const void* in = blockIdx.y ? in1 : in0;
    bf16* outT = blockIdx.y ? outT1 : outT0;
    int idx = blockIdx.x * 256 + threadIdx.x;   // over H*E*D/4
    int i4 = idx * 4;
    int h = i4 >> 17;            // E*D = 131072
    int rem = i4 & 131071;
    int e = rem >> 7;            // D = 128
    int d = rem & 127;
    size_t ob = ((size_t)h * DD + d) * EE + e;
    if (*mode) {
        bf16x4 v = *(const bf16x4*)((const bf16*)in + i4);
        outT[ob]          = v[0];
        outT[ob + EE]     = v[1];
        outT[ob + 2 * EE] = v[2];
        outT[ob + 3 * EE] = v[3];
    } else {
        float4 v = *(const float4*)((const float*)in + i4);
        outT[ob]          = (bf16)v.x;
        outT[ob + EE]     = (bf16)v.y;
        outT[ob + 2 * EE] = (bf16)v.z;
        outT[ob + 3 * EE] = (bf16)v.w;
    }
}

// ---------------------------------------------------------------------------
// Fused K/Q projection. z=0: kx = sigmoid(k@w_kx) (+ kxT transposed copy);
// z=1: qx = sigmoid(q@w_qx). X [M,E] (f32 or bf16), WT [H,D,E] bf16.
// ---------------------------------------------------------------------------
__global__ __launch_bounds__(256) void proj_gemm_kernel(const void* __restrict__ K,
                                                        const void* __restrict__ Q,
                                                        const bf16* __restrict__ WKT,
                                                        const bf16* __restrict__ WQT,
                                                        bf16* __restrict__ KXo,
                                                        bf16* __restrict__ QXo,
                                                        bf16* __restrict__ KXTo,
                                                        const int* __restrict__ mode) {
    __shared__ __align__(16) bf16 As[64 * 32];
    __shared__ __align__(16) bf16 Bs[128 * 32];
    const int md = *mode;
    const int z = blockIdx.z;
    const void* X = z ? Q : K;
    bf16* outX = z ? QXo : KXo;
    bf16* outXT = z ? (bf16*)nullptr : KXTo;
    const int t = threadIdx.x;
    const int w = t >> 6, l = t & 63;
    const int lr = l & 15, lg = l >> 4;
    const int h = blockIdx.y;
    const int m0 = blockIdx.x * 64;
    const bf16* WTh = (z ? WQT : WKT) + (size_t)h * DD * EE;

    f32x4 acc[8];
    const f32x4 zero = {0.f, 0.f, 0.f, 0.f};
#pragma unroll
    for (int n = 0; n < 8; n++) acc[n] = zero;

    for (int kt = 0; kt < EE / 32; ++kt) {
        const int k0 = kt * 32;
        __syncthreads();
        {   // stage A: 64 rows x 4 chunks of 8 elems; one chunk per thread
            int row = t >> 2, cc = t & 3;
            bf16x8 v;
            if (md) {
                v = *(const bf16x8*)((const bf16*)X + (size_t)(m0 + row) * EE + k0 + cc * 8);
            } else {
                const float* src = (const float*)X + (size_t)(m0 + row) * EE + k0 + cc * 8;
                float4 f0 = *(const float4*)(src);
                float4 f1 = *(const float4*)(src + 4);
                v[0] = (bf16)f0.x; v[1] = (bf16)f0.y; v[2] = (bf16)f0.z; v[3] = (bf16)f0.w;
                v[4] = (bf16)f1.x; v[5] = (bf16)f1.y; v[6] = (bf16)f1.z; v[7] = (bf16)f1.w;
            }
            *(bf16x8*)(As + row * 32 + (((cc ^ (row & 3))) << 3)) = v;
        }
#pragma unroll
        for (int p = 0; p < 2; p++) {   // stage B: 128 rows x 4 chunks
            int id = p * 256 + t;
            int row = id >> 2, cc = id & 3;
            bf16x8 v = *(const bf16x8*)(WTh + (size_t)row * EE + k0 + cc * 8);
            *(bf16x8*)(Bs + row * 32 + (((cc ^ (row & 3))) << 3)) = v;
        }
        __syncthreads();
        const int arow = w * 16 + lr;
        bf16x8 a = *(const bf16x8*)(As + arow * 32 + (((lg ^ (arow & 3))) << 3));
#pragma unroll
        for (int n = 0; n < 8; n++) {
            int brow = n * 16 + lr;
            bf16x8 b = *(const bf16x8*)(Bs + brow * 32 + (((lg ^ (brow & 3))) << 3));
            acc[n] = __builtin_amdgcn_mfma_f32_16x16x32_bf16(a, b, acc[n], 0, 0, 0);
        }
    }
    // epilogue: sigmoid + stores
    const int b_idx = m0 / LL;
    const int l0 = m0 - b_idx * LL;
#pragma unroll
    for (int n = 0; n < 8; n++) {
        const int col = n * 16 + lr;
        float s[4];
#pragma unroll
        for (int j = 0; j < 4; j++) {
            s[j] = 1.0f / (1.0f + __expf(-acc[n][j]));
            int mrow = m0 + w * 16 + lg * 4 + j;
            outX[((size_t)h * MM + mrow) * DD + col] = (bf16)s[j];
        }
        if (outXT) {
            bf16x4 pk;
            pk[0] = (bf16)s[0]; pk[1] = (bf16)s[1]; pk[2] = (bf16)s[2]; pk[3] = (bf16)s[3];
            int lrow = l0 + w * 16 + lg * 4;
            *(bf16x4*)(outXT + (((size_t)h * BB + b_idx) * DD + col) * LL + lrow) = pk;
        }
    }
}

// ---------------------------------------------------------------------------
// attention: QX,KX [H, M, D] bf16; KXT [H, B, D, L] bf16 -> AO [M, H*D] bf16
// grid (L/QBLK, B*H); 512 threads = 8 waves. LDS double-buffered K/V +
// register prefetch; 1 barrier per KV tile.
// Softmax WITHOUT max-tracking: scores = qx.kx/sqrt(128) with qx,kx in (0,1)
// => s in (0, 11.32], exp(s) <= 8.2e4, sum <= 1.7e8: f32-safe, p>=1 no
// underflow. Row-sums kept as per-lane partials, reduced once in epilogue.
// ---------------------------------------------------------------------------
__global__ __launch_bounds__(512, 4) void attn_kernel(const bf16* __restrict__ QX,
                                                      const bf16* __restrict__ KX,
                                                      const bf16* __restrict__ KXT,
                                                      bf16* __restrict__ AO) {
    __shared__ __align__(16) bf16 Kl[2][KVBLK * 128];   // 32 KiB
    __shared__ __align__(16) bf16 Vt[2][128 * KVBLK];   // 32 KiB
    __shared__ __align__(16) bf16 Pl[8][16 * 64];       // 16 KiB
    const int t = threadIdx.x;
    const int w = t >> 6, l = t & 63;
    const int lr = l & 15, lg = l >> 4;
    const int bh = blockIdx.y;
    const int h = bh & 7, b = bh >> 3;
    const int q0 = blockIdx.x * QBLK;
    // exp(s/sqrt(128)) = exp2(s * c2), c2 = log2(e)/sqrt(128)
    const float c2 = 0.12751920678739807f;
    const bf16* qxh = QX + ((size_t)h * MM + b * LL) * DD;
    const bf16* kxh = KX + ((size_t)h * MM + b * LL) * DD;
    const bf16* kxt = KXT + ((size_t)(h * BB + b)) * DD * LL;

    // hoisted staging geometry (2 chunks each for K and V per thread)
    const int kid1 = 512 + t;
    const int krow0 = t >> 4,    kcc0 = t & 15;
    const int krow1 = kid1 >> 4, kcc1 = kid1 & 15;
    const int vrow0 = t >> 3,    vcc0 = t & 7;
    const int vrow1 = kid1 >> 3, vcc1 = kid1 & 7;
    const bf16* kp0 = kxh + (size_t)krow0 * DD + kcc0 * 8;
    const bf16* kp1 = kxh + (size_t)krow1 * DD + kcc1 * 8;
    const bf16* vp0 = kxt + (size_t)vrow0 * LL + vcc0 * 8;
    const bf16* vp1 = kxt + (size_t)vrow1 * LL + vcc1 * 8;
    const int kw0 = krow0 * 128 + ((kcc0 ^ (krow0 & 15)) << 3);
    const int kw1 = krow1 * 128 + ((kcc1 ^ (krow1 & 15)) << 3);
    const int vw0 = vrow0 * 64 + ((vcc0 ^ (vrow0 & 7)) << 3);
    const int vw1 = vrow1 * 64 + ((vcc1 ^ (vrow1 & 7)) << 3);

    // Q fragments, register resident
    bf16x8 qf[4];
    const int qrow = q0 + w * 16 + lr;
#pragma unroll
    for (int s = 0; s < 4; s++)
        qf[s] = *(const bf16x8*)(qxh + (size_t)qrow * DD + s * 32 + lg * 8);

    // prologue: tile 0 -> regs -> buf0; issue tile-1 loads
    bf16x8 rk0 = *(const bf16x8*)(kp0);
    bf16x8 rk1 = *(const bf16x8*)(kp1);
    bf16x8 rv0 = *(const bf16x8*)(vp0);
    bf16x8 rv1 = *(const bf16x8*)(vp1);
    *(bf16x8*)(Kl[0] + kw0) = rk0;
    *(bf16x8*)(Kl[0] + kw1) = rk1;
    *(bf16x8*)(Vt[0] + vw0) = rv0;
    *(bf16x8*)(Vt[0] + vw1) = rv1;
    rk0 = *(const bf16x8*)(kp0 + (size_t)KVBLK * DD);
    rk1 = *(const bf16x8*)(kp1 + (size_t)KVBLK * DD);
    rv0 = *(const bf16x8*)(vp0 + KVBLK);
    rv1 = *(const bf16x8*)(vp1 + KVBLK);
    __syncthreads();

    f32x4 oacc[8];
    const f32x4 zero = {0.f, 0.f, 0.f, 0.f};
#pragma unroll
    for (int n = 0; n < 8; n++) oacc[n] = zero;
    float psum[4] = {0.f, 0.f, 0.f, 0.f};   // per-lane partial row sums

    for (int kt = 0; kt < NT; ++kt) {
        const int cur = kt & 1;
        // stage tile kt+1 into alt buffer; issue loads for tile kt+2
        if (kt + 1 < NT) {
            *(bf16x8*)(Kl[cur ^ 1] + kw0) = rk0;
            *(bf16x8*)(Kl[cur ^ 1] + kw1) = rk1;
            *(bf16x8*)(Vt[cur ^ 1] + vw0) = rv0;
            *(bf16x8*)(Vt[cur ^ 1] + vw1) = rv1;
            if (kt + 2 < NT) {
                const size_t ko = (size_t)(kt + 2) * KVBLK * DD;
                const int vo = (kt + 2) * KVBLK;
                rk0 = *(const bf16x8*)(kp0 + ko);
                rk1 = *(const bf16x8*)(kp1 + ko);
                rv0 = *(const bf16x8*)(vp0 + vo);
                rv1 = *(const bf16x8*)(vp1 + vo);
            }
        }
        const bf16* KlC = Kl[cur];
        const bf16* VtC = Vt[cur];

        // scores: S[16 q x 64 kv] = Q K^T (unscaled)
        f32x4 sa[4];
        __builtin_amdgcn_s_setprio(1);
#pragma unroll
        for (int n = 0; n < 4; n++) {
            sa[n] = zero;
#pragma unroll
            for (int ks = 0; ks < 4; ks++) {
                int brow = n * 16 + lr;
                bf16x8 kb = *(const bf16x8*)(KlC + brow * 128 + ((((ks * 4 + lg) ^ (brow & 15))) << 3));
                sa[n] = __builtin_amdgcn_mfma_f32_16x16x32_bf16(qf[ks], kb, sa[n], 0, 0, 0);
            }
        }
        __builtin_amdgcn_s_setprio(0);
        // p = exp(s/sqrt(128)); accumulate per-lane partial sums; stash bf16 P
#pragma unroll
        for (int n = 0; n < 4; n++) {
#pragma unroll
            for (int j = 0; j < 4; j++) {
                float p = exp2f(sa[n][j] * c2);
                psum[j] += p;
                int prow = lg * 4 + j, pcol = n * 16 + lr;
                Pl[w][prow * 64 + ((((pcol >> 3) ^ (prow & 7))) << 3) + (pcol & 7)] = (bf16)p;
            }
        }
        // wave-local ordering: P scalar-stores above vs vector-loads below
        asm volatile("s_waitcnt lgkmcnt(0)" ::: "memory");
        __builtin_amdgcn_sched_barrier(0);
        // PV: O += P V
        bf16x8 pa0 = *(const bf16x8*)(&Pl[w][lr * 64 + (((lg ^ (lr & 7))) << 3)]);
        bf16x8 pa1 = *(const bf16x8*)(&Pl[w][lr * 64 + ((((4 + lg) ^ (lr & 7))) << 3)]);
        __builtin_amdgcn_s_setprio(1);
#pragma unroll
        for (int n = 0; n < 8; n++) {
            int vrow = n * 16 + lr;
            bf16x8 vb0 = *(const bf16x8*)(VtC + vrow * 64 + (((lg ^ (vrow & 7))) << 3));
            oacc[n] = __builtin_amdgcn_mfma_f32_16x16x32_bf16(pa0, vb0, oacc[n], 0, 0, 0);
            bf16x8 vb1 = *(const bf16x8*)(VtC + vrow * 64 + ((((4 + lg) ^ (vrow & 7))) << 3));
            oacc[n] = __builtin_amdgcn_mfma_f32_16x16x32_bf16(pa1, vb1, oacc[n], 0, 0, 0);
        }
        __builtin_amdgcn_s_setprio(0);
        __syncthreads();
    }
    // epilogue: one row-sum reduction, then scale
    float linv[4];
#pragma unroll
    for (int j = 0; j < 4; j++) linv[j] = 1.0f / rowsum16(psum[j]);
    const int arow = b * LL + q0 + w * 16;
#pragma unroll
    for (int n = 0; n < 8; n++) {
        const int col = h * DD + n * 16 + lr;
#pragma unroll
        for (int j = 0; j < 4; j++) {
            float o = oacc[n][j] * linv[j];
            AO[(size_t)(arow + lg * 4 + j) * (HH * DD) + col] = (bf16)o;
        }
    }
}

// ---------------------------------------------------------------------------
// final projection: AO [M,1024] bf16 @ proj_w^T + bias -> d_out FLOAT [M,1024]
// ---------------------------------------------------------------------------
__global__ __launch_bounds__(256) void out_gemm_kernel(const bf16* __restrict__ A,
                                                       const void* __restrict__ PW,
                                                       const void* __restrict__ PB,
                                                       float* __restrict__ Cout,
                                                       const int* __restrict__ mode) {
    __shared__ __align__(16) bf16 As[64 * 32];
    __shared__ __align__(16) bf16 Bs[128 * 32];
    const int md = *mode;
    const int t = threadIdx.x;
    const int w = t >> 6, l = t & 63;
    const int lr = l & 15, lg = l >> 4;
    const int m0 = blockIdx.x * 64;
    const int n0 = blockIdx.y * 128;

    f32x4 acc[8];
    const f32x4 zero = {0.f, 0.f, 0.f, 0.f};
#pragma unroll
    for (int n = 0; n < 8; n++) acc[n] = zero;

    for (int kt = 0; kt < (HH * DD) / 32; ++kt) {
        const int k0 = kt * 32;
        __syncthreads();
        {   // stage A (bf16 source)
            int row = t >> 2, cc = t & 3;
            bf16x8 v = *(const bf16x8*)(A + (size_t)(m0 + row) * (HH * DD) + k0 + cc * 8);
            *(bf16x8*)(As + row * 32 + (((cc ^ (row & 3))) << 3)) = v;
        }
#pragma unroll
        for (int p = 0; p < 2; p++) {   // stage B from proj_w
            int id = p * 256 + t;
            int row = id >> 2, cc = id & 3;
            bf16x8 v;
            if (md) {
                v = *(const bf16x8*)((const bf16*)PW + (size_t)(n0 + row) * (HH * DD) + k0 + cc * 8);
            } else {
                const float* src = (const float*)PW + (size_t)(n0 + row) * (HH * DD) + k0 + cc * 8;
                float4 f0 = *(const float4*)(src);
                float4 f1 = *(const float4*)(src + 4);
                v[0] = (bf16)f0.x; v[1] = (bf16)f0.y; v[2] = (bf16)f0.z; v[3] = (bf16)f0.w;
                v[4] = (bf16)f1.x; v[5] = (bf16)f1.y; v[6] = (bf16)f1.z; v[7] = (bf16)f1.w;
            }
            *(bf16x8*)(Bs + row * 32 + (((cc ^ (row & 3))) << 3)) = v;
        }
        __syncthreads();
        const int arow = w * 16 + lr;
        bf16x8 a = *(const bf16x8*)(As + arow * 32 + (((lg ^ (arow & 3))) << 3));
#pragma unroll
        for (int n = 0; n < 8; n++) {
            int brow = n * 16 + lr;
            bf16x8 b = *(const bf16x8*)(Bs + brow * 32 + (((lg ^ (brow & 3))) << 3));
            acc[n] = __builtin_amdgcn_mfma_f32_16x16x32_bf16(a, b, acc[n], 0, 0, 0);
        }
    }
#pragma unroll
    for (int n = 0; n < 8; n++) {
        const int gcol = n0 + n * 16 + lr;
        const float bias = md ? (float)((const bf16*)PB)[gcol] : ((const float*)PB)[gcol];
#pragma unroll
        for (int j = 0; j < 4; j++) {
            int grow = m0 + w * 16 + lg * 4 + j;
            Cout[(size_t)grow * OO + gcol] = acc[n][j] + bias;   // f32 out
        }
    }
}

extern "C" void kernel_launch(void* const* d_in, const int* in_sizes, int n_in,
                              void* d_out, int out_size, void* d_ws, size_t ws_size,
                              hipStream_t stream) {
    (void)in_sizes; (void)n_in;
    float* out = (float*)d_out;

    const size_t NEED = ((size_t)(2 + 2 + 16 + 16 + 16 + 16) << 20) + 256;
    if (ws_size < NEED) {
        hipLaunchKernelGGL(fill_kernel, dim3((out_size + 255) / 256), dim3(256), 0, stream,
                           out, (float)(ws_size >> 20), out_size);
        return;
    }

    int* mode = (int*)d_ws;
    bf16* base = (bf16*)((char*)d_ws + 256);
    bf16* wkT = base;                              // [H, D, E]   2 MiB
    bf16* wqT = wkT + (size_t)HH * DD * EE;        // [H, D, E]   2 MiB
    bf16* kx  = wqT + (size_t)HH * DD * EE;        // [H, M, D]  16 MiB
    bf16* qx  = kx  + (size_t)HH * MM * DD;        // [H, M, D]  16 MiB
    bf16* kxT = qx  + (size_t)HH * MM * DD;        // [H, B, D, L] 16 MiB
    bf16* ao  = kxT + (size_t)HH * MM * DD;        // [M, H*D]   16 MiB

    hipLaunchKernelGGL(detect_kernel, dim3(1), dim3(64), 0, stream, (const u16*)d_in[0], mode);
    hipLaunchKernelGGL(wtrans_kernel, dim3(HH * EE * DD / 4 / 256, 2), dim3(256), 0, stream,
                       d_in[2], d_in[3], wkT, wqT, mode);
    hipLaunchKernelGGL(proj_gemm_kernel, dim3(MM / 64, HH, 2), dim3(256), 0, stream,
                       d_in[0], d_in[1], wkT, wqT, kx, qx, kxT, mode);
    hipLaunchKernelGGL(attn_kernel, dim3(LL / QBLK, BB * HH), dim3(512), 0, stream, qx, kx, kxT, ao);
    hipLaunchKernelGGL(out_gemm_kernel, dim3(MM / 64, OO / 128), dim3(256), 0, stream, ao, d_in[4], d_in[5], out, mode);
}

// Round 7
// 223.838 us; speedup vs baseline: 1.4633x; 1.1124x over previous
//
#include <hip/hip_runtime.h>

#define BB 4
#define LL 2048
#define EE 1024
#define HH 8
#define DD 128
#define OO 1024
#define MM (BB*LL)   // 8192
#define ND (HH*DD)   // 1024

#define QBLK 128
#define KVBLK 64
#define NT (LL / KVBLK)

typedef __bf16 bf16;
typedef unsigned short u16;
typedef __bf16 bf16x8 __attribute__((ext_vector_type(8)));
typedef __bf16 bf16x4 __attribute__((ext_vector_type(4)));
typedef float  f32x4  __attribute__((ext_vector_type(4)));

__device__ __forceinline__ float rowsum16(float v) {
    v += __shfl_xor(v, 1);
    v += __shfl_xor(v, 2);
    v += __shfl_xor(v, 4);
    v += __shfl_xor(v, 8);
    return v;
}

// async global->LDS, 16B per lane; LDS dest = wave-uniform base + lane*16
__device__ __forceinline__ void gl16(const bf16* g, bf16* l) {
#if __has_builtin(__builtin_amdgcn_global_load_lds)
    __builtin_amdgcn_global_load_lds((const __attribute__((address_space(1))) char*)g,
                                     (__attribute__((address_space(3))) char*)l, 16, 0, 0);
#else
    *(bf16x8*)l = *(const bf16x8*)g;
#endif
}

// ---------------------------------------------------------------------------
// dtype detector: bf16 N(0,1) data -> nearly all u16 exponent fields in
// [117,132]; f32 data -> only ~half. mode=1 => bf16 inputs.
// ---------------------------------------------------------------------------
__global__ void detect_kernel(const u16* __restrict__ data, int* __restrict__ mode) {
    if (threadIdx.x == 0 && blockIdx.x == 0) {
        int cnt = 0;
        for (int i = 0; i < 512; i++) {
            int e = (data[i] >> 7) & 0xFF;
            if (e >= 117 && e <= 132) cnt++;
        }
        *mode = (cnt > 400) ? 1 : 0;
    }
}

__global__ __launch_bounds__(256) void fill_kernel(float* __restrict__ out, float v, int n) {
    int i = blockIdx.x * 256 + threadIdx.x;
    if (i < n) out[i] = v;
}

// ---------------------------------------------------------------------------
// elementwise cast (f32->bf16 or bf16 copy), 8 elems/thread
// ---------------------------------------------------------------------------
__global__ __launch_bounds__(256) void cast_kernel(const void* __restrict__ src,
                                                   bf16* __restrict__ dst,
                                                   int count8,
                                                   const int* __restrict__ mode) {
    int i = blockIdx.x * 256 + threadIdx.x;
    if (i >= count8) return;
    if (*mode) {
        *(bf16x8*)(dst + (size_t)i * 8) = *(const bf16x8*)((const bf16*)src + (size_t)i * 8);
    } else {
        const float* s = (const float*)src + (size_t)i * 8;
        float4 f0 = *(const float4*)s;
        float4 f1 = *(const float4*)(s + 4);
        bf16x8 v;
        v[0] = (bf16)f0.x; v[1] = (bf16)f0.y; v[2] = (bf16)f0.z; v[3] = (bf16)f0.w;
        v[4] = (bf16)f1.x; v[5] = (bf16)f1.y; v[6] = (bf16)f1.z; v[7] = (bf16)f1.w;
        *(bf16x8*)(dst + (size_t)i * 8) = v;
    }
}

// ---------------------------------------------------------------------------
// w [H, E, D] (f32 or bf16)  ->  wT [H, D, E] bf16   (both weights, y=which)
// ---------------------------------------------------------------------------
__global__ __launch_bounds__(256) void wtrans_kernel(const void* __restrict__ in0,
                                                     const void* __restrict__ in1,
                                                     bf16* __restrict__ outT0,
                                                     bf16* __restrict__ outT1,
                                                     const int* __restrict__ mode) {
    const void* in = blockIdx.y ? in1 : in0;
    bf16* outT = blockIdx.y ? outT1 : outT0;
    int idx = blockIdx.x * 256 + threadIdx.x;   // over H*E*D/4
    int i4 = idx * 4;
    int h = i4 >> 17;            // E*D = 131072
    int rem = i4 & 131071;
    int e = rem >> 7;            // D = 128
    int d = rem & 127;
    size_t ob = ((size_t)h * DD + d) * EE + e;
    if (*mode) {
        bf16x4 v = *(const bf16x4*)((const bf16*)in + i4);
        outT[ob]          = v[0];
        outT[ob + EE]     = v[1];
        outT[ob + 2 * EE] = v[2];
        outT[ob + 3 * EE] = v[3];
    } else {
        float4 v = *(const float4*)((const float*)in + i4);
        outT[ob]          = (bf16)v.x;
        outT[ob + EE]     = (bf16)v.y;
        outT[ob + 2 * EE] = (bf16)v.z;
        outT[ob + 3 * EE] = (bf16)v.w;
    }
}

// ---------------------------------------------------------------------------
// Unified 8192x1024x1024 GEMM, C = A @ BT^T.  A [M,1024] bf16, BT [1024,1024]
// bf16 (B^T rows). 128x128 tile, BK=64, 256 thr = 4 waves (2x2 of 64x64).
// global_load_lds width16 with inverse-swizzled global source + swizzled
// ds_read (chunk ^= row&7).  Grid (8 n-tiles, 64 m-tiles), XCD-grouped remap.
// epi: 0 = sigmoid -> outBF [M,ND] + outT [H,B,D,L]; 1 = sigmoid -> outBF;
//      2 = +bias -> outF f32 [M,OO].
// ---------------------------------------------------------------------------
__global__ __launch_bounds__(256) void gemm_kernel(const bf16* __restrict__ A,
                                                   const bf16* __restrict__ BT,
                                                   bf16* __restrict__ outBF,
                                                   bf16* __restrict__ outT,
                                                   float* __restrict__ outF,
                                                   const void* __restrict__ PB,
                                                   const int* __restrict__ mode,
                                                   const int epi) {
    __shared__ __align__(16) bf16 As[128 * 64];
    __shared__ __align__(16) bf16 Bs[128 * 64];
    const int t = threadIdx.x;
    const int w = t >> 6, l = t & 63;
    const int lr = l & 15, lg = l >> 4;
    const int wr = w >> 1, wc = w & 1;
    // XCD-grouped remap (bijective; 512 blocks): XCD j handles m-tiles 8j..8j+7
    const int o = blockIdx.x + (blockIdx.y << 3);
    const int mt = (o & 7) * 8 + ((o >> 3) & 7);
    const int ntile = o >> 6;
    const int m0 = mt * 128, n0 = ntile * 128;

    f32x4 acc[4][4];
    const f32x4 zero = {0.f, 0.f, 0.f, 0.f};
#pragma unroll
    for (int i = 0; i < 4; i++)
#pragma unroll
        for (int j = 0; j < 4; j++) acc[i][j] = zero;

    for (int kt = 0; kt < 16; ++kt) {
        const int k0 = kt * 64;
        __syncthreads();
#pragma unroll
        for (int p = 0; p < 4; p++) {
            const int id = p * 256 + t;
            const int row = id >> 3;
            const int s = id & 7;
            const int c = s ^ (row & 7);   // inverse-swizzled source chunk
            gl16(A + (size_t)(m0 + row) * 1024 + k0 + c * 8, As + (p * 256 + w * 64) * 8);
            gl16(BT + (size_t)(n0 + row) * 1024 + k0 + c * 8, Bs + (p * 256 + w * 64) * 8);
        }
        __syncthreads();
        bf16x8 af[4][2], bg[4][2];
#pragma unroll
        for (int i = 0; i < 4; i++) {
            const int ar = wr * 64 + i * 16 + lr;
#pragma unroll
            for (int ks = 0; ks < 2; ks++)
                af[i][ks] = *(const bf16x8*)(As + ar * 64 + (((ks * 4 + lg) ^ (ar & 7)) << 3));
        }
#pragma unroll
        for (int j = 0; j < 4; j++) {
            const int br = wc * 64 + j * 16 + lr;
#pragma unroll
            for (int ks = 0; ks < 2; ks++)
                bg[j][ks] = *(const bf16x8*)(Bs + br * 64 + (((ks * 4 + lg) ^ (br & 7)) << 3));
        }
#pragma unroll
        for (int i = 0; i < 4; i++)
#pragma unroll
            for (int j = 0; j < 4; j++) {
                acc[i][j] = __builtin_amdgcn_mfma_f32_16x16x32_bf16(af[i][0], bg[j][0], acc[i][j], 0, 0, 0);
                acc[i][j] = __builtin_amdgcn_mfma_f32_16x16x32_bf16(af[i][1], bg[j][1], acc[i][j], 0, 0, 0);
            }
    }

    if (epi < 2) {
        const int b_idx = m0 >> 11;     // block spans one batch row-range
        const int h = n0 >> 7;          // block spans exactly one head
#pragma unroll
        for (int i = 0; i < 4; i++) {
#pragma unroll
            for (int j = 0; j < 4; j++) {
                const int gr = m0 + wr * 64 + i * 16 + lg * 4;
                const int gc = n0 + wc * 64 + j * 16 + lr;
                float s0 = 1.0f / (1.0f + __expf(-acc[i][j][0]));
                float s1 = 1.0f / (1.0f + __expf(-acc[i][j][1]));
                float s2 = 1.0f / (1.0f + __expf(-acc[i][j][2]));
                float s3 = 1.0f / (1.0f + __expf(-acc[i][j][3]));
                outBF[(size_t)gr * ND + gc]           = (bf16)s0;
                outBF[(size_t)(gr + 1) * ND + gc]     = (bf16)s1;
                outBF[(size_t)(gr + 2) * ND + gc]     = (bf16)s2;
                outBF[(size_t)(gr + 3) * ND + gc]     = (bf16)s3;
                if (epi == 0) {
                    bf16x4 pk;
                    pk[0] = (bf16)s0; pk[1] = (bf16)s1; pk[2] = (bf16)s2; pk[3] = (bf16)s3;
                    const int d = gc & 127;
                    const int lrow = gr & 2047;
                    *(bf16x4*)(outT + (((size_t)(h * BB + b_idx)) * DD + d) * LL + lrow) = pk;
                }
            }
        }
    } else {
        const int md = *mode;
#pragma unroll
        for (int j = 0; j < 4; j++) {
            const int gc = n0 + wc * 64 + j * 16 + lr;
            const float bias = md ? (float)((const bf16*)PB)[gc] : ((const float*)PB)[gc];
#pragma unroll
            for (int i = 0; i < 4; i++) {
                const int gr = m0 + wr * 64 + i * 16 + lg * 4;
#pragma unroll
                for (int reg = 0; reg < 4; reg++)
                    outF[(size_t)(gr + reg) * OO + gc] = acc[i][j][reg] + bias;
            }
        }
    }
}

// ---------------------------------------------------------------------------
// attention: QX,KX [M, ND] bf16 (head h at col h*128); KXT [H, B, D, L] bf16
// -> AO [M, ND] bf16.  grid (L/QBLK, B*H); 512 threads = 8 waves.
// LDS double-buffered K/V + register prefetch; 1 barrier per KV tile.
// No-max softmax (scores in (0, 11.32]); deferred row-sum reduction.
// ---------------------------------------------------------------------------
__global__ __launch_bounds__(512, 4) void attn_kernel(const bf16* __restrict__ QX,
                                                      const bf16* __restrict__ KX,
                                                      const bf16* __restrict__ KXT,
                                                      bf16* __restrict__ AO) {
    __shared__ __align__(16) bf16 Kl[2][KVBLK * 128];   // 32 KiB
    __shared__ __align__(16) bf16 Vt[2][128 * KVBLK];   // 32 KiB
    __shared__ __align__(16) bf16 Pl[8][16 * 64];       // 16 KiB
    const int t = threadIdx.x;
    const int w = t >> 6, l = t & 63;
    const int lr = l & 15, lg = l >> 4;
    const int bh = blockIdx.y;
    const int h = bh & 7, b = bh >> 3;
    const int q0 = blockIdx.x * QBLK;
    // exp(s/sqrt(128)) = exp2(s * c2), c2 = log2(e)/sqrt(128)
    const float c2 = 0.12751920678739807f;
    const bf16* qxh = QX + (size_t)(b * LL) * ND + h * DD;
    const bf16* kxh = KX + (size_t)(b * LL) * ND + h * DD;
    const bf16* kxt = KXT + ((size_t)(h * BB + b)) * DD * LL;

    // hoisted staging geometry (2 chunks each for K and V per thread)
    const int kid1 = 512 + t;
    const int krow0 = t >> 4,    kcc0 = t & 15;
    const int krow1 = kid1 >> 4, kcc1 = kid1 & 15;
    const int vrow0 = t >> 3,    vcc0 = t & 7;
    const int vrow1 = kid1 >> 3, vcc1 = kid1 & 7;
    const bf16* kp0 = kxh + (size_t)krow0 * ND + kcc0 * 8;
    const bf16* kp1 = kxh + (size_t)krow1 * ND + kcc1 * 8;
    const bf16* vp0 = kxt + (size_t)vrow0 * LL + vcc0 * 8;
    const bf16* vp1 = kxt + (size_t)vrow1 * LL + vcc1 * 8;
    const int kw0 = krow0 * 128 + ((kcc0 ^ (krow0 & 15)) << 3);
    const int kw1 = krow1 * 128 + ((kcc1 ^ (krow1 & 15)) << 3);
    const int vw0 = vrow0 * 64 + ((vcc0 ^ (vrow0 & 7)) << 3);
    const int vw1 = vrow1 * 64 + ((vcc1 ^ (vrow1 & 7)) << 3);

    // Q fragments, register resident
    bf16x8 qf[4];
    const int qrow = q0 + w * 16 + lr;
#pragma unroll
    for (int s = 0; s < 4; s++)
        qf[s] = *(const bf16x8*)(qxh + (size_t)qrow * ND + s * 32 + lg * 8);

    // prologue: tile 0 -> regs -> buf0; issue tile-1 loads
    bf16x8 rk0 = *(const bf16x8*)(kp0);
    bf16x8 rk1 = *(const bf16x8*)(kp1);
    bf16x8 rv0 = *(const bf16x8*)(vp0);
    bf16x8 rv1 = *(const bf16x8*)(vp1);
    *(bf16x8*)(Kl[0] + kw0) = rk0;
    *(bf16x8*)(Kl[0] + kw1) = rk1;
    *(bf16x8*)(Vt[0] + vw0) = rv0;
    *(bf16x8*)(Vt[0] + vw1) = rv1;
    rk0 = *(const bf16x8*)(kp0 + (size_t)KVBLK * ND);
    rk1 = *(const bf16x8*)(kp1 + (size_t)KVBLK * ND);
    rv0 = *(const bf16x8*)(vp0 + KVBLK);
    rv1 = *(const bf16x8*)(vp1 + KVBLK);
    __syncthreads();

    f32x4 oacc[8];
    const f32x4 zero = {0.f, 0.f, 0.f, 0.f};
#pragma unroll
    for (int n = 0; n < 8; n++) oacc[n] = zero;
    float psum[4] = {0.f, 0.f, 0.f, 0.f};   // per-lane partial row sums

    for (int kt = 0; kt < NT; ++kt) {
        const int cur = kt & 1;
        if (kt + 1 < NT) {
            *(bf16x8*)(Kl[cur ^ 1] + kw0) = rk0;
            *(bf16x8*)(Kl[cur ^ 1] + kw1) = rk1;
            *(bf16x8*)(Vt[cur ^ 1] + vw0) = rv0;
            *(bf16x8*)(Vt[cur ^ 1] + vw1) = rv1;
            if (kt + 2 < NT) {
                const size_t ko = (size_t)(kt + 2) * KVBLK * ND;
                const int vo = (kt + 2) * KVBLK;
                rk0 = *(const bf16x8*)(kp0 + ko);
                rk1 = *(const bf16x8*)(kp1 + ko);
                rv0 = *(const bf16x8*)(vp0 + vo);
                rv1 = *(const bf16x8*)(vp1 + vo);
            }
        }
        const bf16* KlC = Kl[cur];
        const bf16* VtC = Vt[cur];

        // scores: S[16 q x 64 kv] = Q K^T (unscaled)
        f32x4 sa[4];
        __builtin_amdgcn_s_setprio(1);
#pragma unroll
        for (int n = 0; n < 4; n++) {
            sa[n] = zero;
#pragma unroll
            for (int ks = 0; ks < 4; ks++) {
                int brow = n * 16 + lr;
                bf16x8 kb = *(const bf16x8*)(KlC + brow * 128 + ((((ks * 4 + lg) ^ (brow & 15))) << 3));
                sa[n] = __builtin_amdgcn_mfma_f32_16x16x32_bf16(qf[ks], kb, sa[n], 0, 0, 0);
            }
        }
        __builtin_amdgcn_s_setprio(0);
        // p = exp(s/sqrt(128)); accumulate per-lane partial sums; stash bf16 P
#pragma unroll
        for (int n = 0; n < 4; n++) {
#pragma unroll
            for (int j = 0; j < 4; j++) {
                float p = exp2f(sa[n][j] * c2);
                psum[j] += p;
                int prow = lg * 4 + j, pcol = n * 16 + lr;
                Pl[w][prow * 64 + ((((pcol >> 3) ^ (prow & 7))) << 3) + (pcol & 7)] = (bf16)p;
            }
        }
        // wave-local ordering: P scalar-stores above vs vector-loads below
        asm volatile("s_waitcnt lgkmcnt(0)" ::: "memory");
        __builtin_amdgcn_sched_barrier(0);
        // PV: O += P V
        bf16x8 pa0 = *(const bf16x8*)(&Pl[w][lr * 64 + (((lg ^ (lr & 7))) << 3)]);
        bf16x8 pa1 = *(const bf16x8*)(&Pl[w][lr * 64 + ((((4 + lg) ^ (lr & 7))) << 3)]);
        __builtin_amdgcn_s_setprio(1);
#pragma unroll
        for (int n = 0; n < 8; n++) {
            int vrow = n * 16 + lr;
            bf16x8 vb0 = *(const bf16x8*)(VtC + vrow * 64 + (((lg ^ (vrow & 7))) << 3));
            oacc[n] = __builtin_amdgcn_mfma_f32_16x16x32_bf16(pa0, vb0, oacc[n], 0, 0, 0);
            bf16x8 vb1 = *(const bf16x8*)(VtC + vrow * 64 + ((((4 + lg) ^ (vrow & 7))) << 3));
            oacc[n] = __builtin_amdgcn_mfma_f32_16x16x32_bf16(pa1, vb1, oacc[n], 0, 0, 0);
        }
        __builtin_amdgcn_s_setprio(0);
        __syncthreads();
    }
    // epilogue: one row-sum reduction, then scale
    float linv[4];
#pragma unroll
    for (int j = 0; j < 4; j++) linv[j] = 1.0f / rowsum16(psum[j]);
    const int arow = b * LL + q0 + w * 16;
#pragma unroll
    for (int n = 0; n < 8; n++) {
        const int col = h * DD + n * 16 + lr;
#pragma unroll
        for (int j = 0; j < 4; j++) {
            float o = oacc[n][j] * linv[j];
            AO[(size_t)(arow + lg * 4 + j) * ND + col] = (bf16)o;
        }
    }
}

extern "C" void kernel_launch(void* const* d_in, const int* in_sizes, int n_in,
                              void* d_out, int out_size, void* d_ws, size_t ws_size,
                              hipStream_t stream) {
    (void)in_sizes; (void)n_in;
    float* out = (float*)d_out;

    const size_t NEED = ((size_t)(2 + 2 + 16 + 16 + 16 + 16) << 20) + 256;
    if (ws_size < NEED) {
        hipLaunchKernelGGL(fill_kernel, dim3((out_size + 255) / 256), dim3(256), 0, stream,
                           out, (float)(ws_size >> 20), out_size);
        return;
    }

    int* mode = (int*)d_ws;
    bf16* base = (bf16*)((char*)d_ws + 256);
    bf16* wkT = base;                              // [H, D, E]   2 MiB
    bf16* wqT = wkT + (size_t)HH * DD * EE;        // [H, D, E]   2 MiB
    bf16* kx  = wqT + (size_t)HH * DD * EE;        // [M, ND]    16 MiB
    bf16* qx  = kx  + (size_t)MM * ND;             // [M, ND]    16 MiB
    bf16* kxT = qx  + (size_t)MM * ND;             // [H, B, D, L] 16 MiB
    bf16* ao  = kxT + (size_t)HH * MM * DD;        // [M, ND]    16 MiB
    bf16* sc  = ao;                                // A-cast scratch (dead before attn)
    bf16* pwb = kxT;                               // pw cast (kxT dead after attn)

    hipLaunchKernelGGL(detect_kernel, dim3(1), dim3(64), 0, stream, (const u16*)d_in[0], mode);
    hipLaunchKernelGGL(wtrans_kernel, dim3(HH * EE * DD / 4 / 256, 2), dim3(256), 0, stream,
                       d_in[2], d_in[3], wkT, wqT, mode);
    // k -> bf16, proj-k (sigmoid + kxT)
    hipLaunchKernelGGL(cast_kernel, dim3(MM * EE / 8 / 256), dim3(256), 0, stream,
                       d_in[0], sc, MM * EE / 8, mode);
    hipLaunchKernelGGL(gemm_kernel, dim3(8, 64), dim3(256), 0, stream,
                       sc, wkT, kx, kxT, (float*)nullptr, (const void*)nullptr, mode, 0);
    // q -> bf16, proj-q (sigmoid)
    hipLaunchKernelGGL(cast_kernel, dim3(MM * EE / 8 / 256), dim3(256), 0, stream,
                       d_in[1], sc, MM * EE / 8, mode);
    hipLaunchKernelGGL(gemm_kernel, dim3(8, 64), dim3(256), 0, stream,
                       sc, wqT, qx, (bf16*)nullptr, (float*)nullptr, (const void*)nullptr, mode, 1);
    // attention
    hipLaunchKernelGGL(attn_kernel, dim3(LL / QBLK, BB * HH), dim3(512), 0, stream, qx, kx, kxT, ao);
    // proj_w -> bf16, out-proj (+bias, f32 out)
    hipLaunchKernelGGL(cast_kernel, dim3(OO * ND / 8 / 256), dim3(256), 0, stream,
                       d_in[4], pwb, OO * ND / 8, mode);
    hipLaunchKernelGGL(gemm_kernel, dim3(8, 64), dim3(256), 0, stream,
                       ao, pwb, (bf16*)nullptr, (bf16*)nullptr, out, d_in[5], mode, 2);
}

// Round 8
// 213.937 us; speedup vs baseline: 1.5310x; 1.0463x over previous
//
#include <hip/hip_runtime.h>

#define BB 4
#define LL 2048
#define EE 1024
#define HH 8
#define DD 128
#define OO 1024
#define MM (BB*LL)   // 8192
#define ND (HH*DD)   // 1024

#define QBLK 128
#define KVBLK 64
#define NT (LL / KVBLK)

typedef __bf16 bf16;
typedef unsigned short u16;
typedef __bf16 bf16x8 __attribute__((ext_vector_type(8)));
typedef __bf16 bf16x4 __attribute__((ext_vector_type(4)));
typedef float  f32x4  __attribute__((ext_vector_type(4)));

__device__ __forceinline__ float rowsum16(float v) {
    v += __shfl_xor(v, 1);
    v += __shfl_xor(v, 2);
    v += __shfl_xor(v, 4);
    v += __shfl_xor(v, 8);
    return v;
}

// async global->LDS, 16B per lane; LDS dest = wave-uniform base + lane*16
__device__ __forceinline__ void gl16(const bf16* g, bf16* l) {
#if __has_builtin(__builtin_amdgcn_global_load_lds)
    __builtin_amdgcn_global_load_lds((const __attribute__((address_space(1))) char*)g,
                                     (__attribute__((address_space(3))) char*)l, 16, 0, 0);
#else
    *(bf16x8*)l = *(const bf16x8*)g;
#endif
}

__device__ __forceinline__ bf16x8 cvt8(const float* s) {
    float4 f0 = *(const float4*)s;
    float4 f1 = *(const float4*)(s + 4);
    bf16x8 v;
    v[0] = (bf16)f0.x; v[1] = (bf16)f0.y; v[2] = (bf16)f0.z; v[3] = (bf16)f0.w;
    v[4] = (bf16)f1.x; v[5] = (bf16)f1.y; v[6] = (bf16)f1.z; v[7] = (bf16)f1.w;
    return v;
}

// ---------------------------------------------------------------------------
// dtype detector: bf16 N(0,1) data -> nearly all u16 exponent fields in
// [117,132]; f32 data -> only ~half. mode=1 => bf16 inputs.
// ---------------------------------------------------------------------------
__global__ void detect_kernel(const u16* __restrict__ data, int* __restrict__ mode) {
    if (threadIdx.x == 0 && blockIdx.x == 0) {
        int cnt = 0;
        for (int i = 0; i < 512; i++) {
            int e = (data[i] >> 7) & 0xFF;
            if (e >= 117 && e <= 132) cnt++;
        }
        *mode = (cnt > 400) ? 1 : 0;
    }
}

__global__ __launch_bounds__(256) void fill_kernel(float* __restrict__ out, float v, int n) {
    int i = blockIdx.x * 256 + threadIdx.x;
    if (i < n) out[i] = v;
}

// ---------------------------------------------------------------------------
// w [H, E, D] (f32 or bf16)  ->  wT [H, D, E] bf16   (both weights, y=which)
// ---------------------------------------------------------------------------
__global__ __launch_bounds__(256) void wtrans_kernel(const void* __restrict__ in0,
                                                     const void* __restrict__ in1,
                                                     bf16* __restrict__ outT0,
                                                     bf16* __restrict__ outT1,
                                                     const int* __restrict__ mode) {
    const void* in = blockIdx.y ? in1 : in0;
    bf16* outT = blockIdx.y ? outT1 : outT0;
    int idx = blockIdx.x * 256 + threadIdx.x;   // over H*E*D/4
    int i4 = idx * 4;
    int h = i4 >> 17;            // E*D = 131072
    int rem = i4 & 131071;
    int e = rem >> 7;            // D = 128
    int d = rem & 127;
    size_t ob = ((size_t)h * DD + d) * EE + e;
    if (*mode) {
        bf16x4 v = *(const bf16x4*)((const bf16*)in + i4);
        outT[ob]          = v[0];
        outT[ob + EE]     = v[1];
        outT[ob + 2 * EE] = v[2];
        outT[ob + 3 * EE] = v[3];
    } else {
        float4 v = *(const float4*)((const float*)in + i4);
        outT[ob]          = (bf16)v.x;
        outT[ob + EE]     = (bf16)v.y;
        outT[ob + 2 * EE] = (bf16)v.z;
        outT[ob + 3 * EE] = (bf16)v.w;
    }
}

// ---------------------------------------------------------------------------
// Unified 8192x1024x1024 GEMM, C = A @ BT^T.  Either operand may be f32
// (reg-staged with cast) or bf16 (global_load_lds, inverse-swizzled source).
// 128x128 tile, BK=64, 256 thr = 4 waves (2x2 of 64x64).
// epi: 0 = sigmoid -> outBF [M,ND] + outT [H,B,D,L]; 1 = sigmoid -> outBF;
//      2 = +bias -> outF f32 [M,OO].
// aBf = (epi==2) ? 1 : md;  bBf = (epi==2) ? md : 1.
// ---------------------------------------------------------------------------
__global__ __launch_bounds__(256) void gemm_kernel(const void* __restrict__ A,
                                                   const void* __restrict__ BT,
                                                   bf16* __restrict__ outBF,
                                                   bf16* __restrict__ outT,
                                                   float* __restrict__ outF,
                                                   const void* __restrict__ PB,
                                                   const int* __restrict__ mode,
                                                   const int epi) {
    __shared__ __align__(16) bf16 As[128 * 64];
    __shared__ __align__(16) bf16 Bs[128 * 64];
    const int md = *mode;
    const int aBf = (epi == 2) ? 1 : md;
    const int bBf = (epi == 2) ? md : 1;
    const int t = threadIdx.x;
    const int w = t >> 6, l = t & 63;
    const int lr = l & 15, lg = l >> 4;
    const int wr = w >> 1, wc = w & 1;
    // XCD-grouped remap (bijective; 512 blocks): XCD j handles m-tiles 8j..8j+7
    const int o = blockIdx.x + (blockIdx.y << 3);
    const int mt = (o & 7) * 8 + ((o >> 3) & 7);
    const int ntile = o >> 6;
    const int m0 = mt * 128, n0 = ntile * 128;

    f32x4 acc[4][4];
    const f32x4 zero = {0.f, 0.f, 0.f, 0.f};
#pragma unroll
    for (int i = 0; i < 4; i++)
#pragma unroll
        for (int j = 0; j < 4; j++) acc[i][j] = zero;

    for (int kt = 0; kt < 16; ++kt) {
        const int k0 = kt * 64;
        __syncthreads();
        if (aBf) {
#pragma unroll
            for (int p = 0; p < 4; p++) {
                const int id = p * 256 + t;
                const int row = id >> 3;
                const int c = (id & 7) ^ (row & 7);   // inverse-swizzled source chunk
                gl16((const bf16*)A + (size_t)(m0 + row) * 1024 + k0 + c * 8,
                     As + (p * 256 + w * 64) * 8);
            }
        } else {
#pragma unroll
            for (int p = 0; p < 4; p++) {
                const int id = p * 256 + t;
                const int row = id >> 3;
                const int cc = id & 7;                // linear source, swizzled dest
                bf16x8 v = cvt8((const float*)A + (size_t)(m0 + row) * 1024 + k0 + cc * 8);
                *(bf16x8*)(As + row * 64 + ((cc ^ (row & 7)) << 3)) = v;
            }
        }
        if (bBf) {
#pragma unroll
            for (int p = 0; p < 4; p++) {
                const int id = p * 256 + t;
                const int row = id >> 3;
                const int c = (id & 7) ^ (row & 7);
                gl16((const bf16*)BT + (size_t)(n0 + row) * 1024 + k0 + c * 8,
                     Bs + (p * 256 + w * 64) * 8);
            }
        } else {
#pragma unroll
            for (int p = 0; p < 4; p++) {
                const int id = p * 256 + t;
                const int row = id >> 3;
                const int cc = id & 7;
                bf16x8 v = cvt8((const float*)BT + (size_t)(n0 + row) * 1024 + k0 + cc * 8);
                *(bf16x8*)(Bs + row * 64 + ((cc ^ (row & 7)) << 3)) = v;
            }
        }
        __syncthreads();
        bf16x8 af[4][2], bg[4][2];
#pragma unroll
        for (int i = 0; i < 4; i++) {
            const int ar = wr * 64 + i * 16 + lr;
#pragma unroll
            for (int ks = 0; ks < 2; ks++)
                af[i][ks] = *(const bf16x8*)(As + ar * 64 + (((ks * 4 + lg) ^ (ar & 7)) << 3));
        }
#pragma unroll
        for (int j = 0; j < 4; j++) {
            const int br = wc * 64 + j * 16 + lr;
#pragma unroll
            for (int ks = 0; ks < 2; ks++)
                bg[j][ks] = *(const bf16x8*)(Bs + br * 64 + (((ks * 4 + lg) ^ (br & 7)) << 3));
        }
#pragma unroll
        for (int i = 0; i < 4; i++)
#pragma unroll
            for (int j = 0; j < 4; j++) {
                acc[i][j] = __builtin_amdgcn_mfma_f32_16x16x32_bf16(af[i][0], bg[j][0], acc[i][j], 0, 0, 0);
                acc[i][j] = __builtin_amdgcn_mfma_f32_16x16x32_bf16(af[i][1], bg[j][1], acc[i][j], 0, 0, 0);
            }
    }

    if (epi < 2) {
        const int b_idx = m0 >> 11;     // block spans one batch row-range
        const int h = n0 >> 7;          // block spans exactly one head
#pragma unroll
        for (int i = 0; i < 4; i++) {
#pragma unroll
            for (int j = 0; j < 4; j++) {
                const int gr = m0 + wr * 64 + i * 16 + lg * 4;
                const int gc = n0 + wc * 64 + j * 16 + lr;
                float s0 = 1.0f / (1.0f + __expf(-acc[i][j][0]));
                float s1 = 1.0f / (1.0f + __expf(-acc[i][j][1]));
                float s2 = 1.0f / (1.0f + __expf(-acc[i][j][2]));
                float s3 = 1.0f / (1.0f + __expf(-acc[i][j][3]));
                outBF[(size_t)gr * ND + gc]           = (bf16)s0;
                outBF[(size_t)(gr + 1) * ND + gc]     = (bf16)s1;
                outBF[(size_t)(gr + 2) * ND + gc]     = (bf16)s2;
                outBF[(size_t)(gr + 3) * ND + gc]     = (bf16)s3;
                if (epi == 0) {
                    bf16x4 pk;
                    pk[0] = (bf16)s0; pk[1] = (bf16)s1; pk[2] = (bf16)s2; pk[3] = (bf16)s3;
                    const int d = gc & 127;
                    const int lrow = gr & 2047;
                    *(bf16x4*)(outT + (((size_t)(h * BB + b_idx)) * DD + d) * LL + lrow) = pk;
                }
            }
        }
    } else {
#pragma unroll
        for (int j = 0; j < 4; j++) {
            const int gc = n0 + wc * 64 + j * 16 + lr;
            const float bias = md ? (float)((const bf16*)PB)[gc] : ((const float*)PB)[gc];
#pragma unroll
            for (int i = 0; i < 4; i++) {
                const int gr = m0 + wr * 64 + i * 16 + lg * 4;
#pragma unroll
                for (int reg = 0; reg < 4; reg++)
                    outF[(size_t)(gr + reg) * OO + gc] = acc[i][j][reg] + bias;
            }
        }
    }
}

// ---------------------------------------------------------------------------
// attention: QX,KX [M, ND] bf16 (head h at col h*128); KXT [H, B, D, L] bf16
// -> AO [M, ND] bf16.  1-D grid 512, XCD-chunked remap: XCD x owns bh 4x..4x+3
// (its K/V ~4MB stays in that XCD's L2).  512 threads = 8 waves.
// LDS double-buffered K/V + register prefetch; 1 barrier per KV tile.
// No-max softmax (scores in (0, 11.32]); deferred row-sum reduction.
// ---------------------------------------------------------------------------
__global__ __launch_bounds__(512, 4) void attn_kernel(const bf16* __restrict__ QX,
                                                      const bf16* __restrict__ KX,
                                                      const bf16* __restrict__ KXT,
                                                      bf16* __restrict__ AO) {
    __shared__ __align__(16) bf16 Kl[2][KVBLK * 128];   // 32 KiB
    __shared__ __align__(16) bf16 Vt[2][128 * KVBLK];   // 32 KiB
    __shared__ __align__(16) bf16 Pl[8][16 * 64];       // 16 KiB
    const int t = threadIdx.x;
    const int w = t >> 6, l = t & 63;
    const int lr = l & 15, lg = l >> 4;
    // XCD-chunked remap: dispatched bid -> orig linear id (bh-major)
    const int bid = blockIdx.x;
    const int orig = (bid & 7) * 64 + (bid >> 3);
    const int bh = orig >> 4;
    const int h = bh & 7, b = bh >> 3;
    const int q0 = (orig & 15) * QBLK;
    // exp(s/sqrt(128)) = exp2(s * c2), c2 = log2(e)/sqrt(128)
    const float c2 = 0.12751920678739807f;
    const bf16* qxh = QX + (size_t)(b * LL) * ND + h * DD;
    const bf16* kxh = KX + (size_t)(b * LL) * ND + h * DD;
    const bf16* kxt = KXT + ((size_t)(h * BB + b)) * DD * LL;

    // hoisted staging geometry (2 chunks each for K and V per thread)
    const int kid1 = 512 + t;
    const int krow0 = t >> 4,    kcc0 = t & 15;
    const int krow1 = kid1 >> 4, kcc1 = kid1 & 15;
    const int vrow0 = t >> 3,    vcc0 = t & 7;
    const int vrow1 = kid1 >> 3, vcc1 = kid1 & 7;
    const bf16* kp0 = kxh + (size_t)krow0 * ND + kcc0 * 8;
    const bf16* kp1 = kxh + (size_t)krow1 * ND + kcc1 * 8;
    const bf16* vp0 = kxt + (size_t)vrow0 * LL + vcc0 * 8;
    const bf16* vp1 = kxt + (size_t)vrow1 * LL + vcc1 * 8;
    const int kw0 = krow0 * 128 + ((kcc0 ^ (krow0 & 15)) << 3);
    const int kw1 = krow1 * 128 + ((kcc1 ^ (krow1 & 15)) << 3);
    const int vw0 = vrow0 * 64 + ((vcc0 ^ (vrow0 & 7)) << 3);
    const int vw1 = vrow1 * 64 + ((vcc1 ^ (vrow1 & 7)) << 3);

    // Q fragments, register resident
    bf16x8 qf[4];
    const int qrow = q0 + w * 16 + lr;
#pragma unroll
    for (int s = 0; s < 4; s++)
        qf[s] = *(const bf16x8*)(qxh + (size_t)qrow * ND + s * 32 + lg * 8);

    // prologue: tile 0 -> regs -> buf0; issue tile-1 loads
    bf16x8 rk0 = *(const bf16x8*)(kp0);
    bf16x8 rk1 = *(const bf16x8*)(kp1);
    bf16x8 rv0 = *(const bf16x8*)(vp0);
    bf16x8 rv1 = *(const bf16x8*)(vp1);
    *(bf16x8*)(Kl[0] + kw0) = rk0;
    *(bf16x8*)(Kl[0] + kw1) = rk1;
    *(bf16x8*)(Vt[0] + vw0) = rv0;
    *(bf16x8*)(Vt[0] + vw1) = rv1;
    rk0 = *(const bf16x8*)(kp0 + (size_t)KVBLK * ND);
    rk1 = *(const bf16x8*)(kp1 + (size_t)KVBLK * ND);
    rv0 = *(const bf16x8*)(vp0 + KVBLK);
    rv1 = *(const bf16x8*)(vp1 + KVBLK);
    __syncthreads();

    f32x4 oacc[8];
    const f32x4 zero = {0.f, 0.f, 0.f, 0.f};
#pragma unroll
    for (int n = 0; n < 8; n++) oacc[n] = zero;
    float psum[4] = {0.f, 0.f, 0.f, 0.f};   // per-lane partial row sums

    for (int kt = 0; kt < NT; ++kt) {
        const int cur = kt & 1;
        if (kt + 1 < NT) {
            *(bf16x8*)(Kl[cur ^ 1] + kw0) = rk0;
            *(bf16x8*)(Kl[cur ^ 1] + kw1) = rk1;
            *(bf16x8*)(Vt[cur ^ 1] + vw0) = rv0;
            *(bf16x8*)(Vt[cur ^ 1] + vw1) = rv1;
            if (kt + 2 < NT) {
                const size_t ko = (size_t)(kt + 2) * KVBLK * ND;
                const int vo = (kt + 2) * KVBLK;
                rk0 = *(const bf16x8*)(kp0 + ko);
                rk1 = *(const bf16x8*)(kp1 + ko);
                rv0 = *(const bf16x8*)(vp0 + vo);
                rv1 = *(const bf16x8*)(vp1 + vo);
            }
        }
        const bf16* KlC = Kl[cur];
        const bf16* VtC = Vt[cur];

        // scores: S[16 q x 64 kv] = Q K^T (unscaled)
        f32x4 sa[4];
        __builtin_amdgcn_s_setprio(1);
#pragma unroll
        for (int n = 0; n < 4; n++) {
            sa[n] = zero;
#pragma unroll
            for (int ks = 0; ks < 4; ks++) {
                int brow = n * 16 + lr;
                bf16x8 kb = *(const bf16x8*)(KlC + brow * 128 + ((((ks * 4 + lg) ^ (brow & 15))) << 3));
                sa[n] = __builtin_amdgcn_mfma_f32_16x16x32_bf16(qf[ks], kb, sa[n], 0, 0, 0);
            }
        }
        __builtin_amdgcn_s_setprio(0);
        // p = exp(s/sqrt(128)); accumulate per-lane partial sums; stash bf16 P
#pragma unroll
        for (int n = 0; n < 4; n++) {
#pragma unroll
            for (int j = 0; j < 4; j++) {
                float p = exp2f(sa[n][j] * c2);
                psum[j] += p;
                int prow = lg * 4 + j, pcol = n * 16 + lr;
                Pl[w][prow * 64 + ((((pcol >> 3) ^ (prow & 7))) << 3) + (pcol & 7)] = (bf16)p;
            }
        }
        // wave-local ordering: P scalar-stores above vs vector-loads below
        asm volatile("s_waitcnt lgkmcnt(0)" ::: "memory");
        __builtin_amdgcn_sched_barrier(0);
        // PV: O += P V
        bf16x8 pa0 = *(const bf16x8*)(&Pl[w][lr * 64 + (((lg ^ (lr & 7))) << 3)]);
        bf16x8 pa1 = *(const bf16x8*)(&Pl[w][lr * 64 + ((((4 + lg) ^ (lr & 7))) << 3)]);
        __builtin_amdgcn_s_setprio(1);
#pragma unroll
        for (int n = 0; n < 8; n++) {
            int vrow = n * 16 + lr;
            bf16x8 vb0 = *(const bf16x8*)(VtC + vrow * 64 + (((lg ^ (vrow & 7))) << 3));
            oacc[n] = __builtin_amdgcn_mfma_f32_16x16x32_bf16(pa0, vb0, oacc[n], 0, 0, 0);
            bf16x8 vb1 = *(const bf16x8*)(VtC + vrow * 64 + ((((4 + lg) ^ (vrow & 7))) << 3));
            oacc[n] = __builtin_amdgcn_mfma_f32_16x16x32_bf16(pa1, vb1, oacc[n], 0, 0, 0);
        }
        __builtin_amdgcn_s_setprio(0);
        __syncthreads();
    }
    // epilogue: one row-sum reduction, then scale
    float linv[4];
#pragma unroll
    for (int j = 0; j < 4; j++) linv[j] = 1.0f / rowsum16(psum[j]);
    const int arow = b * LL + q0 + w * 16;
#pragma unroll
    for (int n = 0; n < 8; n++) {
        const int col = h * DD + n * 16 + lr;
#pragma unroll
        for (int j = 0; j < 4; j++) {
            float o = oacc[n][j] * linv[j];
            AO[(size_t)(arow + lg * 4 + j) * ND + col] = (bf16)o;
        }
    }
}

extern "C" void kernel_launch(void* const* d_in, const int* in_sizes, int n_in,
                              void* d_out, int out_size, void* d_ws, size_t ws_size,
                              hipStream_t stream) {
    (void)in_sizes; (void)n_in;
    float* out = (float*)d_out;

    const size_t NEED = ((size_t)(2 + 2 + 16 + 16 + 16 + 16) << 20) + 256;
    if (ws_size < NEED) {
        hipLaunchKernelGGL(fill_kernel, dim3((out_size + 255) / 256), dim3(256), 0, stream,
                           out, (float)(ws_size >> 20), out_size);
        return;
    }

    int* mode = (int*)d_ws;
    bf16* base = (bf16*)((char*)d_ws + 256);
    bf16* wkT = base;                              // [H, D, E]   2 MiB
    bf16* wqT = wkT + (size_t)HH * DD * EE;        // [H, D, E]   2 MiB
    bf16* kx  = wqT + (size_t)HH * DD * EE;        // [M, ND]    16 MiB
    bf16* qx  = kx  + (size_t)MM * ND;             // [M, ND]    16 MiB
    bf16* kxT = qx  + (size_t)MM * ND;             // [H, B, D, L] 16 MiB
    bf16* ao  = kxT + (size_t)HH * MM * DD;        // [M, ND]    16 MiB

    hipLaunchKernelGGL(detect_kernel, dim3(1), dim3(64), 0, stream, (const u16*)d_in[0], mode);
    hipLaunchKernelGGL(wtrans_kernel, dim3(HH * EE * DD / 4 / 256, 2), dim3(256), 0, stream,
                       d_in[2], d_in[3], wkT, wqT, mode);
    // proj-k (sigmoid + kxT); A = k (f32 reg-staged or bf16 gload)
    hipLaunchKernelGGL(gemm_kernel, dim3(8, 64), dim3(256), 0, stream,
                       d_in[0], wkT, kx, kxT, (float*)nullptr, (const void*)nullptr, mode, 0);
    // proj-q (sigmoid)
    hipLaunchKernelGGL(gemm_kernel, dim3(8, 64), dim3(256), 0, stream,
                       d_in[1], wqT, qx, (bf16*)nullptr, (float*)nullptr, (const void*)nullptr, mode, 1);
    // attention
    hipLaunchKernelGGL(attn_kernel, dim3(512), dim3(512), 0, stream, qx, kx, kxT, ao);
    // out-proj (+bias, f32 out); B = proj_w (f32 reg-staged or bf16 gload)
    hipLaunchKernelGGL(gemm_kernel, dim3(8, 64), dim3(256), 0, stream,
                       ao, d_in[4], (bf16*)nullptr, (bf16*)nullptr, out, d_in[5], mode, 2);
}

// Round 9
// 199.372 us; speedup vs baseline: 1.6428x; 1.0731x over previous
//
#include <hip/hip_runtime.h>

#define BB 4
#define LL 2048
#define EE 1024
#define HH 8
#define DD 128
#define OO 1024
#define MM (BB*LL)   // 8192
#define ND (HH*DD)   // 1024

#define QBLK 128
#define KVBLK 64
#define NT (LL / KVBLK)

// log2(e)/sqrt(128): folded into qx at proj-q epilogue
#define C2 0.12751920678739807f

typedef __bf16 bf16;
typedef unsigned short u16;
typedef __bf16 bf16x8 __attribute__((ext_vector_type(8)));
typedef __bf16 bf16x4 __attribute__((ext_vector_type(4)));
typedef float  f32x4  __attribute__((ext_vector_type(4)));

// async global->LDS, 16B per lane; LDS dest = wave-uniform base + lane*16
__device__ __forceinline__ void gl16(const bf16* g, bf16* l) {
#if __has_builtin(__builtin_amdgcn_global_load_lds)
    __builtin_amdgcn_global_load_lds((const __attribute__((address_space(1))) char*)g,
                                     (__attribute__((address_space(3))) char*)l, 16, 0, 0);
#else
    *(bf16x8*)l = *(const bf16x8*)g;
#endif
}

__device__ __forceinline__ bf16x8 cvt8(const float* s) {
    float4 f0 = *(const float4*)s;
    float4 f1 = *(const float4*)(s + 4);
    bf16x8 v;
    v[0] = (bf16)f0.x; v[1] = (bf16)f0.y; v[2] = (bf16)f0.z; v[3] = (bf16)f0.w;
    v[4] = (bf16)f1.x; v[5] = (bf16)f1.y; v[6] = (bf16)f1.z; v[7] = (bf16)f1.w;
    return v;
}

// ---------------------------------------------------------------------------
// dtype detector: bf16 N(0,1) data -> nearly all u16 exponent fields in
// [117,132]; f32 data -> only ~half. mode=1 => bf16 inputs.
// ---------------------------------------------------------------------------
__global__ void detect_kernel(const u16* __restrict__ data, int* __restrict__ mode) {
    if (threadIdx.x == 0 && blockIdx.x == 0) {
        int cnt = 0;
        for (int i = 0; i < 512; i++) {
            int e = (data[i] >> 7) & 0xFF;
            if (e >= 117 && e <= 132) cnt++;
        }
        *mode = (cnt > 400) ? 1 : 0;
    }
}

__global__ __launch_bounds__(256) void fill_kernel(float* __restrict__ out, float v, int n) {
    int i = blockIdx.x * 256 + threadIdx.x;
    if (i < n) out[i] = v;
}

// ---------------------------------------------------------------------------
// w [H, E, D] (f32 or bf16)  ->  wT [H, D, E] bf16   (both weights, y=which)
// ---------------------------------------------------------------------------
__global__ __launch_bounds__(256) void wtrans_kernel(const void* __restrict__ in0,
                                                     const void* __restrict__ in1,
                                                     bf16* __restrict__ outT0,
                                                     bf16* __restrict__ outT1,
                                                     const int* __restrict__ mode) {
    const void* in = blockIdx.y ? in1 : in0;
    bf16* outT = blockIdx.y ? outT1 : outT0;
    int idx = blockIdx.x * 256 + threadIdx.x;   // over H*E*D/4
    int i4 = idx * 4;
    int h = i4 >> 17;            // E*D = 131072
    int rem = i4 & 131071;
    int e = rem >> 7;            // D = 128
    int d = rem & 127;
    size_t ob = ((size_t)h * DD + d) * EE + e;
    if (*mode) {
        bf16x4 v = *(const bf16x4*)((const bf16*)in + i4);
        outT[ob]          = v[0];
        outT[ob + EE]     = v[1];
        outT[ob + 2 * EE] = v[2];
        outT[ob + 3 * EE] = v[3];
    } else {
        float4 v = *(const float4*)((const float*)in + i4);
        outT[ob]          = (bf16)v.x;
        outT[ob + EE]     = (bf16)v.y;
        outT[ob + 2 * EE] = (bf16)v.z;
        outT[ob + 3 * EE] = (bf16)v.w;
    }
}

// ---------------------------------------------------------------------------
// Unified 8192x1024x1024 GEMM, C = A @ BT^T.  Either operand may be f32
// (reg-staged with cast) or bf16 (global_load_lds, inverse-swizzled source).
// 128x128 tile, BK=64, 256 thr = 4 waves (2x2 of 64x64).
// epi==3: merged projections, 1024 blocks; half 0: sigmoid -> outBF0 + outT
//         (kxT layout), half 1: sigmoid*C2 -> outBF1 (qx pre-scaled for attn).
// epi==2: out-proj, 512 blocks: +bias -> outF (f32).
// ---------------------------------------------------------------------------
__global__ __launch_bounds__(256) void gemm_kernel(const void* __restrict__ A0,
                                                   const void* __restrict__ A1,
                                                   const void* __restrict__ BT0,
                                                   const void* __restrict__ BT1,
                                                   bf16* __restrict__ outBF0,
                                                   bf16* __restrict__ outBF1,
                                                   bf16* __restrict__ outT,
                                                   float* __restrict__ outF,
                                                   const void* __restrict__ PB,
                                                   const int* __restrict__ mode,
                                                   const int epi) {
    __shared__ __align__(16) bf16 As[128 * 64];
    __shared__ __align__(16) bf16 Bs[128 * 64];
    const int md = *mode;
    const int aBf = (epi == 2) ? 1 : md;
    const int bBf = (epi == 2) ? md : 1;
    const int t = threadIdx.x;
    const int w = t >> 6, l = t & 63;
    const int lr = l & 15, lg = l >> 4;
    const int wr = w >> 1, wc = w & 1;
    // XCD-grouped remap (bijective per 512-block half)
    const int o = blockIdx.x + (blockIdx.y << 3);
    const int half = (epi == 3) ? (o >> 9) : 0;
    const int oo = o & 511;
    const int mt = (oo & 7) * 8 + ((oo >> 3) & 7);
    const int ntile = oo >> 6;
    const int m0 = mt * 128, n0 = ntile * 128;
    const void* A = half ? A1 : A0;
    const void* BT = half ? BT1 : BT0;

    f32x4 acc[4][4];
    const f32x4 zero = {0.f, 0.f, 0.f, 0.f};
#pragma unroll
    for (int i = 0; i < 4; i++)
#pragma unroll
        for (int j = 0; j < 4; j++) acc[i][j] = zero;

    for (int kt = 0; kt < 16; ++kt) {
        const int k0 = kt * 64;
        __syncthreads();
        if (aBf) {
#pragma unroll
            for (int p = 0; p < 4; p++) {
                const int id = p * 256 + t;
                const int row = id >> 3;
                const int c = (id & 7) ^ (row & 7);   // inverse-swizzled source chunk
                gl16((const bf16*)A + (size_t)(m0 + row) * 1024 + k0 + c * 8,
                     As + (p * 256 + w * 64) * 8);
            }
        } else {
#pragma unroll
            for (int p = 0; p < 4; p++) {
                const int id = p * 256 + t;
                const int row = id >> 3;
                const int cc = id & 7;                // linear source, swizzled dest
                bf16x8 v = cvt8((const float*)A + (size_t)(m0 + row) * 1024 + k0 + cc * 8);
                *(bf16x8*)(As + row * 64 + ((cc ^ (row & 7)) << 3)) = v;
            }
        }
        if (bBf) {
#pragma unroll
            for (int p = 0; p < 4; p++) {
                const int id = p * 256 + t;
                const int row = id >> 3;
                const int c = (id & 7) ^ (row & 7);
                gl16((const bf16*)BT + (size_t)(n0 + row) * 1024 + k0 + c * 8,
                     Bs + (p * 256 + w * 64) * 8);
            }
        } else {
#pragma unroll
            for (int p = 0; p < 4; p++) {
                const int id = p * 256 + t;
                const int row = id >> 3;
                const int cc = id & 7;
                bf16x8 v = cvt8((const float*)BT + (size_t)(n0 + row) * 1024 + k0 + cc * 8);
                *(bf16x8*)(Bs + row * 64 + ((cc ^ (row & 7)) << 3)) = v;
            }
        }
        __syncthreads();
        bf16x8 af[4][2], bg[4][2];
#pragma unroll
        for (int i = 0; i < 4; i++) {
            const int ar = wr * 64 + i * 16 + lr;
#pragma unroll
            for (int ks = 0; ks < 2; ks++)
                af[i][ks] = *(const bf16x8*)(As + ar * 64 + (((ks * 4 + lg) ^ (ar & 7)) << 3));
        }
#pragma unroll
        for (int j = 0; j < 4; j++) {
            const int br = wc * 64 + j * 16 + lr;
#pragma unroll
            for (int ks = 0; ks < 2; ks++)
                bg[j][ks] = *(const bf16x8*)(Bs + br * 64 + (((ks * 4 + lg) ^ (br & 7)) << 3));
        }
#pragma unroll
        for (int i = 0; i < 4; i++)
#pragma unroll
            for (int j = 0; j < 4; j++) {
                acc[i][j] = __builtin_amdgcn_mfma_f32_16x16x32_bf16(af[i][0], bg[j][0], acc[i][j], 0, 0, 0);
                acc[i][j] = __builtin_amdgcn_mfma_f32_16x16x32_bf16(af[i][1], bg[j][1], acc[i][j], 0, 0, 0);
            }
    }

    if (epi == 3) {
        bf16* outBF = half ? outBF1 : outBF0;
        const float mulf = half ? C2 : 1.0f;
        const int b_idx = m0 >> 11;     // block spans one batch row-range
        const int h = n0 >> 7;          // block spans exactly one head
#pragma unroll
        for (int i = 0; i < 4; i++) {
#pragma unroll
            for (int j = 0; j < 4; j++) {
                const int gr = m0 + wr * 64 + i * 16 + lg * 4;
                const int gc = n0 + wc * 64 + j * 16 + lr;
                float s0 = mulf / (1.0f + __expf(-acc[i][j][0]));
                float s1 = mulf / (1.0f + __expf(-acc[i][j][1]));
                float s2 = mulf / (1.0f + __expf(-acc[i][j][2]));
                float s3 = mulf / (1.0f + __expf(-acc[i][j][3]));
                outBF[(size_t)gr * ND + gc]           = (bf16)s0;
                outBF[(size_t)(gr + 1) * ND + gc]     = (bf16)s1;
                outBF[(size_t)(gr + 2) * ND + gc]     = (bf16)s2;
                outBF[(size_t)(gr + 3) * ND + gc]     = (bf16)s3;
                if (!half) {
                    bf16x4 pk;
                    pk[0] = (bf16)s0; pk[1] = (bf16)s1; pk[2] = (bf16)s2; pk[3] = (bf16)s3;
                    const int d = gc & 127;
                    const int lrow = gr & 2047;
                    *(bf16x4*)(outT + (((size_t)(h * BB + b_idx)) * DD + d) * LL + lrow) = pk;
                }
            }
        }
    } else {
#pragma unroll
        for (int j = 0; j < 4; j++) {
            const int gc = n0 + wc * 64 + j * 16 + lr;
            const float bias = md ? (float)((const bf16*)PB)[gc] : ((const float*)PB)[gc];
#pragma unroll
            for (int i = 0; i < 4; i++) {
                const int gr = m0 + wr * 64 + i * 16 + lg * 4;
#pragma unroll
                for (int reg = 0; reg < 4; reg++)
                    outF[(size_t)(gr + reg) * OO + gc] = acc[i][j][reg] + bias;
            }
        }
    }
}

// ---------------------------------------------------------------------------
// attention: QX (pre-scaled by C2), KX [M, ND] bf16; KXT [H, B, D, L] bf16
// -> AO [M, ND] bf16.  1-D grid 512, XCD-chunked remap.  512 thr = 8 waves.
// SWAPPED-operand scheme: QK^T = mfma(K, Q) so each lane holds P for a single
// q-row (q = lane&15, kv = n*16+lg*4+j): P-stores are 4x ds_write_b64, psum is
// one scalar, PV = mfma(V^T, P) gives O^T with d contiguous per lane (packed
// bf16x4 global stores).  No-max softmax (p = exp2(s), s in (0,16.4]).
// ---------------------------------------------------------------------------
__global__ __launch_bounds__(512, 4) void attn_kernel(const bf16* __restrict__ QX,
                                                      const bf16* __restrict__ KX,
                                                      const bf16* __restrict__ KXT,
                                                      bf16* __restrict__ AO) {
    __shared__ __align__(16) bf16 Kl[2][KVBLK * 128];   // 32 KiB
    __shared__ __align__(16) bf16 Vt[2][128 * KVBLK];   // 32 KiB
    __shared__ __align__(16) bf16 Pl[8][16 * 64];       // 16 KiB
    const int t = threadIdx.x;
    const int w = t >> 6, l = t & 63;
    const int lr = l & 15, lg = l >> 4;
    // XCD-chunked remap: dispatched bid -> orig linear id (bh-major)
    const int bid = blockIdx.x;
    const int orig = (bid & 7) * 64 + (bid >> 3);
    const int bh = orig >> 4;
    const int h = bh & 7, b = bh >> 3;
    const int q0 = (orig & 15) * QBLK;
    const bf16* qxh = QX + (size_t)(b * LL) * ND + h * DD;
    const bf16* kxh = KX + (size_t)(b * LL) * ND + h * DD;
    const bf16* kxt = KXT + ((size_t)(h * BB + b)) * DD * LL;

    // hoisted staging geometry (2 chunks each for K and V per thread)
    const int kid1 = 512 + t;
    const int krow0 = t >> 4,    kcc0 = t & 15;
    const int krow1 = kid1 >> 4, kcc1 = kid1 & 15;
    const int vrow0 = t >> 3,    vcc0 = t & 7;
    const int vrow1 = kid1 >> 3, vcc1 = kid1 & 7;
    const bf16* kp0 = kxh + (size_t)krow0 * ND + kcc0 * 8;
    const bf16* kp1 = kxh + (size_t)krow1 * ND + kcc1 * 8;
    const bf16* vp0 = kxt + (size_t)vrow0 * LL + vcc0 * 8;
    const bf16* vp1 = kxt + (size_t)vrow1 * LL + vcc1 * 8;
    const int kw0 = krow0 * 128 + ((kcc0 ^ (krow0 & 15)) << 3);
    const int kw1 = krow1 * 128 + ((kcc1 ^ (krow1 & 15)) << 3);
    const int vw0 = vrow0 * 64 + ((vcc0 ^ (vrow0 & 7)) << 3);
    const int vw1 = vrow1 * 64 + ((vcc1 ^ (vrow1 & 7)) << 3);

    // Q fragments (q row = lane&15), register resident; QX pre-scaled by C2
    bf16x8 qf[4];
    const int qrow = q0 + w * 16 + lr;
#pragma unroll
    for (int s = 0; s < 4; s++)
        qf[s] = *(const bf16x8*)(qxh + (size_t)qrow * ND + s * 32 + lg * 8);

    // prologue: tile 0 -> regs -> buf0; issue tile-1 loads
    bf16x8 rk0 = *(const bf16x8*)(kp0);
    bf16x8 rk1 = *(const bf16x8*)(kp1);
    bf16x8 rv0 = *(const bf16x8*)(vp0);
    bf16x8 rv1 = *(const bf16x8*)(vp1);
    *(bf16x8*)(Kl[0] + kw0) = rk0;
    *(bf16x8*)(Kl[0] + kw1) = rk1;
    *(bf16x8*)(Vt[0] + vw0) = rv0;
    *(bf16x8*)(Vt[0] + vw1) = rv1;
    rk0 = *(const bf16x8*)(kp0 + (size_t)KVBLK * ND);
    rk1 = *(const bf16x8*)(kp1 + (size_t)KVBLK * ND);
    rv0 = *(const bf16x8*)(vp0 + KVBLK);
    rv1 = *(const bf16x8*)(vp1 + KVBLK);
    __syncthreads();

    f32x4 oacc[8];   // O^T: oacc[n][reg] = O[d = n*16+lg*4+reg][q = lr]
    const f32x4 zero = {0.f, 0.f, 0.f, 0.f};
#pragma unroll
    for (int n = 0; n < 8; n++) oacc[n] = zero;
    float psum = 0.f;   // per-lane partial row sum for q = lr

    for (int kt = 0; kt < NT; ++kt) {
        const int cur = kt & 1;
        if (kt + 1 < NT) {
            *(bf16x8*)(Kl[cur ^ 1] + kw0) = rk0;
            *(bf16x8*)(Kl[cur ^ 1] + kw1) = rk1;
            *(bf16x8*)(Vt[cur ^ 1] + vw0) = rv0;
            *(bf16x8*)(Vt[cur ^ 1] + vw1) = rv1;
            if (kt + 2 < NT) {
                const size_t ko = (size_t)(kt + 2) * KVBLK * ND;
                const int vo = (kt + 2) * KVBLK;
                rk0 = *(const bf16x8*)(kp0 + ko);
                rk1 = *(const bf16x8*)(kp1 + ko);
                rv0 = *(const bf16x8*)(vp0 + vo);
                rv1 = *(const bf16x8*)(vp1 + vo);
            }
        }
        const bf16* KlC = Kl[cur];
        const bf16* VtC = Vt[cur];

        // swapped QK^T: sa[n] = P^T block; lane: q=lr, kv = n*16+lg*4+j
        f32x4 sa[4];
        __builtin_amdgcn_s_setprio(1);
#pragma unroll
        for (int n = 0; n < 4; n++) {
            sa[n] = zero;
#pragma unroll
            for (int ks = 0; ks < 4; ks++) {
                int arow = n * 16 + lr;   // kv row
                bf16x8 kb = *(const bf16x8*)(KlC + arow * 128 + ((((ks * 4 + lg) ^ (arow & 15))) << 3));
                sa[n] = __builtin_amdgcn_mfma_f32_16x16x32_bf16(kb, qf[ks], sa[n], 0, 0, 0);
            }
        }
        __builtin_amdgcn_s_setprio(0);
        // p = exp2(s); per-lane psum; pack 4 kv-contiguous bf16 per ds_write_b64
#pragma unroll
        for (int n = 0; n < 4; n++) {
            bf16x4 pk;
#pragma unroll
            for (int j = 0; j < 4; j++) {
                float p = exp2f(sa[n][j]);
                psum += p;
                pk[j] = (bf16)p;
            }
            const int chunk = (2 * n + (lg >> 1)) ^ (lr & 7);
            *(bf16x4*)(Pl[w] + lr * 64 + chunk * 8 + (lg & 1) * 4) = pk;
        }
        // wave-local ordering: P stores above vs vector-loads below
        asm volatile("s_waitcnt lgkmcnt(0)" ::: "memory");
        __builtin_amdgcn_sched_barrier(0);
        // PV: O^T += V^T P  (A = V^T rows d, B = P rows q)
        bf16x8 pb0 = *(const bf16x8*)(Pl[w] + lr * 64 + (((lg ^ (lr & 7))) << 3));
        bf16x8 pb1 = *(const bf16x8*)(Pl[w] + lr * 64 + ((((4 + lg) ^ (lr & 7))) << 3));
        __builtin_amdgcn_s_setprio(1);
#pragma unroll
        for (int n = 0; n < 8; n++) {
            int vrow = n * 16 + lr;
            bf16x8 vb0 = *(const bf16x8*)(VtC + vrow * 64 + (((lg ^ (vrow & 7))) << 3));
            oacc[n] = __builtin_amdgcn_mfma_f32_16x16x32_bf16(vb0, pb0, oacc[n], 0, 0, 0);
            bf16x8 vb1 = *(const bf16x8*)(VtC + vrow * 64 + ((((4 + lg) ^ (vrow & 7))) << 3));
            oacc[n] = __builtin_amdgcn_mfma_f32_16x16x32_bf16(vb1, pb1, oacc[n], 0, 0, 0);
        }
        __builtin_amdgcn_s_setprio(0);
        __syncthreads();
    }
    // epilogue: reduce psum across the 4 lane-groups holding q = lr
    float tot = psum;
    tot += __shfl_xor(tot, 16);
    tot += __shfl_xor(tot, 32);
    const float linv = 1.0f / tot;
    const int arow = b * LL + q0 + w * 16 + lr;   // one output row per lane
    bf16* aoRow = AO + (size_t)arow * ND + h * DD;
#pragma unroll
    for (int n = 0; n < 8; n++) {
        bf16x4 o;
#pragma unroll
        for (int reg = 0; reg < 4; reg++) o[reg] = (bf16)(oacc[n][reg] * linv);
        *(bf16x4*)(aoRow + n * 16 + lg * 4) = o;
    }
}

extern "C" void kernel_launch(void* const* d_in, const int* in_sizes, int n_in,
                              void* d_out, int out_size, void* d_ws, size_t ws_size,
                              hipStream_t stream) {
    (void)in_sizes; (void)n_in;
    float* out = (float*)d_out;

    const size_t NEED = ((size_t)(2 + 2 + 16 + 16 + 16 + 16) << 20) + 256;
    if (ws_size < NEED) {
        hipLaunchKernelGGL(fill_kernel, dim3((out_size + 255) / 256), dim3(256), 0, stream,
                           out, (float)(ws_size >> 20), out_size);
        return;
    }

    int* mode = (int*)d_ws;
    bf16* base = (bf16*)((char*)d_ws + 256);
    bf16* wkT = base;                              // [H, D, E]   2 MiB
    bf16* wqT = wkT + (size_t)HH * DD * EE;        // [H, D, E]   2 MiB
    bf16* kx  = wqT + (size_t)HH * DD * EE;        // [M, ND]    16 MiB
    bf16* qx  = kx  + (size_t)MM * ND;             // [M, ND]    16 MiB
    bf16* kxT = qx  + (size_t)MM * ND;             // [H, B, D, L] 16 MiB
    bf16* ao  = kxT + (size_t)HH * MM * DD;        // [M, ND]    16 MiB

    hipLaunchKernelGGL(detect_kernel, dim3(1), dim3(64), 0, stream, (const u16*)d_in[0], mode);
    hipLaunchKernelGGL(wtrans_kernel, dim3(HH * EE * DD / 4 / 256, 2), dim3(256), 0, stream,
                       d_in[2], d_in[3], wkT, wqT, mode);
    // merged proj-k (sigmoid + kxT) and proj-q (sigmoid*C2): 1024 blocks
    hipLaunchKernelGGL(gemm_kernel, dim3(8, 128), dim3(256), 0, stream,
                       d_in[0], d_in[1], wkT, wqT, kx, qx, kxT,
                       (float*)nullptr, (const void*)nullptr, mode, 3);
    // attention
    hipLaunchKernelGGL(attn_kernel, dim3(512), dim3(512), 0, stream, qx, kx, kxT, ao);
    // out-proj (+bias, f32 out); B = proj_w (f32 reg-staged or bf16 gload)
    hipLaunchKernelGGL(gemm_kernel, dim3(8, 64), dim3(256), 0, stream,
                       ao, (const void*)nullptr, d_in[4], (const void*)nullptr,
                       (bf16*)nullptr, (bf16*)nullptr, (bf16*)nullptr, out, d_in[5], mode, 2);
}